// Round 5
// baseline (623.076 us; speedup 1.0000x reference)
//
#include <hip/hip_runtime.h>
#include <cstdint>
#include <cstddef>

typedef unsigned long long u64;
typedef unsigned int u32;

#define HCAP 1024
#define HMASK (HCAP - 1)
#define SLICES 2
#define SCAND 192           // per-slice pool capacity
#define CAND 384            // SLICES * SCAND
#define NSLOT 6             // CAND / 64
#define NBINS 4096
#define SEL_THR 1024
#define SEL_TARGET 128

// IoU exactly as reference _box_iou, all f32 IEEE ops (bit-exact, absmax=0 rounds 1-4).
__device__ __forceinline__ float iou_f32(float4 p, float4 t, float area_t) {
  float area1 = (p.z - p.x) * (p.w - p.y);
  float ltx = fmaxf(p.x, t.x);
  float lty = fmaxf(p.y, t.y);
  float rbx = fminf(p.z, t.z);
  float rby = fminf(p.w, t.w);
  float wx = fmaxf(rbx - ltx, 0.0f);
  float wy = fmaxf(rby - lty, 0.0f);
  float inter = wx * wy;
  return inter / (area1 + area_t - inter);
}

__device__ __forceinline__ u64 map_cost(double cur) {
  u64 b = (u64)__double_as_longlong(cur);
  if (b == 0x8000000000000000ull) b = 0;                 // canonicalize -0 -> +0
  return (b >> 63) ? ~b : (b | 0x8000000000000000ull);   // order-exact total map
}
__device__ __forceinline__ double unmap_cost(u64 m) {
  u64 b = (m >> 63) ? (m ^ 0x8000000000000000ull) : ~m;
  return __longlong_as_double((long long)b);
}

// Kernel A: per (slice,row) block. Pool = all cols with iou>0 and bin >= B where
// B = highest bin with suffix-count >= 128  ->  pool SET is a superset of the
// per-slice top-128 by (iou desc, col asc). Union over slices ⊇ global top-128.
__global__ __launch_bounds__(SEL_THR) void select_kernel(const float4* __restrict__ pbox,
                                                         const float4* __restrict__ tbox,
                                                         u64* __restrict__ cand,
                                                         int* __restrict__ ncand,
                                                         int M, int NROWS) {
  __shared__ u32 s_hist[NBINS];
  __shared__ int s_csum[SEL_THR];
  __shared__ int s_red[SEL_THR / 64];
  __shared__ u64 s_pool[SCAND];
  __shared__ int s_n, s_B, s_np;
  const int tid = threadIdx.x;
  const int slice = blockIdx.x, row = blockIdx.y;
  const int sw = (M + SLICES - 1) / SLICES;
  const int base = slice * sw;
  const int send = min(base + sw, M);
  const float4 tb = tbox[row];
  const float area_t = (tb.z - tb.x) * (tb.w - tb.y);

  for (int b = tid; b < NBINS; b += SEL_THR) s_hist[b] = 0;
  if (tid == 0) s_n = 0;
  __syncthreads();

  int mypos = 0;
  for (int j = base + tid; j < send; j += SEL_THR) {
    float io = iou_f32(pbox[j], tb, area_t);
    if (io > 0.0f) { atomicAdd(&s_hist[__float_as_uint(io) >> 18], 1u); ++mypos; }
  }
  for (int off = 32; off; off >>= 1) mypos += __shfl_down(mypos, off);
  if ((tid & 63) == 0) s_red[tid >> 6] = mypos;
  __syncthreads();
  if (tid == 0) {
    int t = 0;
    for (int w2 = 0; w2 < SEL_THR / 64; ++w2) t += s_red[w2];
    s_np = t;
  }
  __syncthreads();
  const int np = s_np;

  // per-thread sum of 4 contiguous bins
  {
    int b0 = tid * 4;
    s_csum[tid] = (int)(s_hist[b0] + s_hist[b0 + 1] + s_hist[b0 + 2] + s_hist[b0 + 3]);
  }
  __syncthreads();

  if (tid < 64) {                       // wave 0: descending suffix scan for threshold
    int B = 0;
    if (np >= SEL_TARGET) {
      int R = 0; bool found = false;
      for (int ch = SEL_THR / 64 - 1; ch >= 0 && !found; --ch) {
        int cum = s_csum[ch * 64 + tid];
        for (int off = 1; off < 64; off <<= 1) {
          int o = __shfl_down(cum, off);
          if (tid + off < 64) cum += o;
        }
        int chunksum = __shfl(cum, 0);
        if (R + chunksum >= SEL_TARGET) {
          u64 m = __ballot(R + cum >= SEL_TARGET);
          int l = 63 - __clzll(m);                    // highest lane with suffix >= target
          int R2 = R + ((l < 63) ? __shfl(cum, l + 1) : 0);
          if (tid == 0) {
            int bb = (ch * 64 + l) * 4;
            int B2 = bb;
            for (int b = bb + 3; b >= bb; --b) {
              R2 += (int)s_hist[b];
              if (R2 >= SEL_TARGET) { B2 = b; break; }
            }
            s_B = B2;
          }
          found = true;
        } else R += chunksum;
      }
      if (!found && tid == 0) s_B = 0;
    } else if (tid == 0) s_B = 0;
  }
  __syncthreads();
  const int B = s_B;

  for (int j = base + tid; j < send; j += SEL_THR) {
    float io = iou_f32(pbox[j], tb, area_t);
    if (io > 0.0f && (int)(__float_as_uint(io) >> 18) >= B) {
      int pos = atomicAdd(&s_n, 1);
      if (pos < SCAND) s_pool[pos] = ((u64)__float_as_uint(io) << 32) | (u32)j;
    }
  }
  __syncthreads();

  if (np < SEL_TARGET && tid < 64) {    // rare zero-fill: first (128-np) zero-iou cols asc
    int need = SEL_TARGET - np, got = 0;
    int base_n = s_n;
    for (int b2 = base; b2 < send && got < need; b2 += 64) {
      int j = b2 + tid;
      float io = (j < send) ? iou_f32(pbox[j], tb, area_t) : -1.0f;
      bool z = (j < send) && (io == 0.0f);
      u64 zm = __ballot(z);
      int rank = (int)__popcll(zm & ((1ull << tid) - 1ull));
      if (z && rank < need - got) {
        int pos = base_n + got + rank;
        if (pos < SCAND) s_pool[pos] = (u64)(u32)j;
      }
      int zn = (int)__popcll(zm);
      if (zn > need - got) zn = need - got;
      got += zn;
    }
    if (tid == 0) s_n = base_n + got;
  }
  __syncthreads();

  int n = s_n; if (n > SCAND) n = SCAND;
  if (tid < n) cand[(size_t)(row * SLICES + slice) * SCAND + tid] = s_pool[tid];
  if (tid == 0) ncand[row * SLICES + slice] = n;
}

#define DPP_STEP(CTRL) do { \
  u32 ohi = (u32)__builtin_amdgcn_update_dpp((int)0xFFFFFFFF, (int)khi, (CTRL), 0xF, 0xF, false); \
  u32 olo = (u32)__builtin_amdgcn_update_dpp((int)0xFFFFFFFF, (int)klo, (CTRL), 0xF, 0xF, false); \
  int ocl =      __builtin_amdgcn_update_dpp((int)0x7FFFFFFF, kcol,     (CTRL), 0xF, 0xF, false); \
  bool lt = (ohi < khi) || (ohi == khi && ((olo < klo) || (olo == klo && ocl < kcol))); \
  if (lt) { khi = ohi; klo = olo; kcol = ocl; } \
} while (0)

// Kernel B: the serial buggy-JV matcher, 1 wave, zero LDS on the fast path.
// Invariants: visited => owned; v!=0 => owned; ownership frozen during a search.
__global__ __launch_bounds__(64) void match_kernel(const float4* __restrict__ pbox,
                                                   const float4* __restrict__ tboxg,
                                                   const u64* __restrict__ cand,
                                                   const int* __restrict__ ncand,
                                                   int* __restrict__ pairs,
                                                   int M, int NROWS) {
  const int lane = threadIdx.x;
  __shared__ u32 h_col[HCAP];
  for (int i = lane; i < HCAP; i += 64) h_col[i] = 0;

  float4 zf = make_float4(0.f, 0.f, 0.f, 0.f);
  float4 tbA = (lane < NROWS) ? tboxg[lane] : zf;
  float4 tbB = (lane + 64 < NROWS) ? tboxg[lane + 64] : zf;

  double u_a = 0.0, u_b = 0.0;          // u[lane+1], u[lane+65]
  int f_a = 0, f_b = 0;                 // in-chain flags
  int oc0 = -1, orow0 = 0, ovis0 = 0; double ov0 = 0.0; float4 ob0 = zf;
  int oc1 = -1, orow1 = 0, ovis1 = 0; double ov1 = 0.0; float4 ob1 = zf;
  int nown = 0;

  int c[NSLOT]; float io[NSLOT]; float4 sbx[NSLOT];
  u64 pf[NSLOT]; u64 tmpk[NSLOT];
  int ncn0, ncn1;
  int row = 1, i0 = 1;
  double u_i0 = 0.0;
  __syncthreads();

  auto decode_and_prep = [&](int nc0, int nc1) {
#pragma unroll
    for (int s = 0; s < NSLOT; ++s) {
      int idx = (s << 6) + lane;
      int within = (idx < SCAND) ? idx : idx - SCAND;
      int lim = (idx < SCAND) ? nc0 : nc1;
      if (within < lim) {
        u64 k = tmpk[s];
        c[s] = (int)(u32)k;
        io[s] = __uint_as_float((u32)(k >> 32));
      } else c[s] = -1;
    }
#pragma unroll
    for (int s = 0; s < NSLOT; ++s) {             // exclude owned (covered by owned-eval)
      if (c[s] < 0) continue;
      u32 key = (u32)(c[s] + 1);
      int h = (int)((key * 2654435761u) >> 22) & HMASK;
      for (;;) {
        u32 cc = h_col[h];
        if (cc == key) { c[s] = -1; break; }
        if (cc == 0u) break;
        h = (h + 1) & HMASK;
      }
    }
#pragma unroll
    for (int s = 0; s < NSLOT; ++s) sbx[s] = pbox[c[s] >= 0 ? c[s] : 0];
  };

  auto stage_row = [&](int r) {
#pragma unroll
    for (int s = 0; s < NSLOT; ++s) tmpk[s] = pf[s];
    decode_and_prep(ncn0, ncn1);
    int nr = (r < NROWS) ? r + 1 : r;
#pragma unroll
    for (int s = 0; s < NSLOT; ++s) pf[s] = cand[(size_t)(nr - 1) * CAND + (s << 6) + lane];
    ncn0 = ncand[2 * (nr - 1)];
    ncn1 = ncand[2 * (nr - 1) + 1];
    f_a = (lane == ((r - 1) & 63)) && (((r - 1) >> 6) == 0);
    f_b = (lane == ((r - 1) & 63)) && (((r - 1) >> 6) == 1);
    u_i0 = 0.0;                          // u[row]==0 at its own search start (proven)
  };

  auto stage_chain = [&](int o) {        // chain row's pool, cold (rare); keeps pf/ncn
#pragma unroll
    for (int s = 0; s < NSLOT; ++s) tmpk[s] = cand[(size_t)(o - 1) * CAND + (s << 6) + lane];
    int c0 = ncand[2 * (o - 1)];
    int c1 = ncand[2 * (o - 1) + 1];
    decode_and_prep(c0, c1);
  };

  // initial staging for row 1
#pragma unroll
  for (int s = 0; s < NSLOT; ++s) pf[s] = cand[(s << 6) + lane];
  ncn0 = ncand[0]; ncn1 = ncand[1];
  stage_row(1);

  for (int guard = 0; guard < 5000; ++guard) {
    // ---- fresh-slot eval: pure registers (v==0, never visited) ----
    u32 bhi = 0xFFFFFFFFu, blo = 0xFFFFFFFFu; int bcol = 0x7fffffff; int bsl = 15;
#pragma unroll
    for (int s = 0; s < NSLOT; ++s) {
      if (c[s] < 0) continue;
      double cur = (-(double)io[s]) - u_i0;          // == ((-io)-u)-0.0 bitwise
      u64 mk = map_cost(cur);
      u32 hi = (u32)(mk >> 32), lo = (u32)mk;
      bool t = (hi < bhi) || (hi == bhi && ((lo < blo) || (lo == blo && c[s] < bcol)));
      if (t) { bhi = hi; blo = lo; bcol = c[s]; bsl = s; }
    }
    // ---- owned eval: registers + readlane'd target box ----
    {
      int li = (i0 - 1) & 63, hb = (i0 - 1) >> 6;
      float tx = __int_as_float(hb ? __builtin_amdgcn_readlane(__float_as_int(tbB.x), li)
                                   : __builtin_amdgcn_readlane(__float_as_int(tbA.x), li));
      float ty = __int_as_float(hb ? __builtin_amdgcn_readlane(__float_as_int(tbB.y), li)
                                   : __builtin_amdgcn_readlane(__float_as_int(tbA.y), li));
      float tz = __int_as_float(hb ? __builtin_amdgcn_readlane(__float_as_int(tbB.z), li)
                                   : __builtin_amdgcn_readlane(__float_as_int(tbA.z), li));
      float tw = __int_as_float(hb ? __builtin_amdgcn_readlane(__float_as_int(tbB.w), li)
                                   : __builtin_amdgcn_readlane(__float_as_int(tbA.w), li));
      float4 tbi = make_float4(tx, ty, tz, tw);
      float ati = (tz - tx) * (tw - ty);
      if (oc0 >= 0 && ovis0 != row) {
        float io2 = iou_f32(ob0, tbi, ati);
        double cur = ((-(double)io2) - u_i0) - ov0;
        u64 mk = map_cost(cur);
        u32 hi = (u32)(mk >> 32), lo = (u32)mk;
        bool t = (hi < bhi) || (hi == bhi && ((lo < blo) || (lo == blo && oc0 < bcol)));
        if (t) { bhi = hi; blo = lo; bcol = oc0; bsl = 6; }
      }
      if (oc1 >= 0 && ovis1 != row) {
        float io2 = iou_f32(ob1, tbi, ati);
        double cur = ((-(double)io2) - u_i0) - ov1;
        u64 mk = map_cost(cur);
        u32 hi = (u32)(mk >> 32), lo = (u32)mk;
        bool t = (hi < bhi) || (hi == bhi && ((lo < blo) || (lo == blo && oc1 < bcol)));
        if (t) { bhi = hi; blo = lo; bcol = oc1; bsl = 7; }
      }
    }
    // ---- 64-lane argmin via DPP (VALU only) ----
    u32 khi = bhi, klo = blo; int kcol = bcol;
    DPP_STEP(0x111); DPP_STEP(0x112); DPP_STEP(0x114); DPP_STEP(0x118);
    DPP_STEP(0x142); DPP_STEP(0x143);
    u32 rhi = (u32)__builtin_amdgcn_readlane((int)khi, 63);
    u32 rlo = (u32)__builtin_amdgcn_readlane((int)klo, 63);
    int jc = __builtin_amdgcn_readlane(kcol, 63);
    const double delta = unmap_cost(((u64)rhi << 32) | (u64)rlo);

    // ---- updates: u[p[used]] += delta ; v[used] -= delta (pre-append used set) ----
    if (f_a) u_a += delta;
    if (f_b) u_b += delta;
    u_i0 += delta;
    if (oc0 >= 0 && ovis0 == row) ov0 -= delta;
    if (oc1 >= 0 && ovis1 == row) ov1 -= delta;

    // ---- winner: prefer owned claimants on exact (key,col) ties (stale-probe safety) ----
    bool eq = (bhi == rhi) && (blo == rlo) && (bcol == jc);
    u64 wown = __ballot(eq && bsl >= 6);
    u64 wany = __ballot(eq);
    u64 wm = wown ? wown : wany;
    int L = (int)__ffsll((long long)wm) - 1;
    L = __builtin_amdgcn_readfirstlane(L);
    int s_w = __builtin_amdgcn_readlane(bsl, L);

    if (s_w >= 6) {
      // chain to owner row
      int o = __builtin_amdgcn_readlane((s_w == 6) ? orow0 : orow1, L);
      o = __builtin_amdgcn_readfirstlane(o);
      if (lane == L) { if (s_w == 6) ovis0 = row; else ovis1 = row; }
      int ol = (o - 1) & 63, oh = (o - 1) >> 6;
      if (lane == ol) { if (oh == 0) f_a = 1; else f_b = 1; }
      double uo = oh ? u_b : u_a;
      int uhi = __builtin_amdgcn_readlane(__double2hiint(uo), ol);
      int ulo = __builtin_amdgcn_readlane(__double2loint(uo), ol);
      u_i0 = __hiloint2double(uhi, ulo);
      i0 = o;
      stage_chain(o);
    } else {
      // augment: way==0 collapses to single assignment p[jc]=row
      if (lane == 0) pairs[row - 1] = jc;
      float4 wb = sbx[0];
      if (bsl == 1) wb = sbx[1];
      if (bsl == 2) wb = sbx[2];
      if (bsl == 3) wb = sbx[3];
      if (bsl == 4) wb = sbx[4];
      if (bsl == 5) wb = sbx[5];
      float4 nb;
      nb.x = __int_as_float(__builtin_amdgcn_readlane(__float_as_int(wb.x), L));
      nb.y = __int_as_float(__builtin_amdgcn_readlane(__float_as_int(wb.y), L));
      nb.z = __int_as_float(__builtin_amdgcn_readlane(__float_as_int(wb.z), L));
      nb.w = __int_as_float(__builtin_amdgcn_readlane(__float_as_int(wb.w), L));
      int ne = nown, nl = ne & 63, nh = ne >> 6;
      if (lane == nl) {
        if (nh == 0) { oc0 = jc; orow0 = row; ovis0 = 0; ov0 = 0.0; ob0 = nb; }
        else         { oc1 = jc; orow1 = row; ovis1 = 0; ov1 = 0.0; ob1 = nb; }
      }
      nown = ne + 1;
      if (lane == 0) {
        u32 key = (u32)(jc + 1);
        int h = (int)((key * 2654435761u) >> 22) & HMASK;
        while (h_col[h] != 0u) h = (h + 1) & HMASK;
        h_col[h] = key;
      }
      if (row == NROWS) break;
      ++row; i0 = row;
      stage_row(row);
    }
  }
}

__global__ __launch_bounds__(256) void loss_kernel(const float4* __restrict__ pbox,
                                                   const float* __restrict__ confs,
                                                   const float4* __restrict__ tbox,
                                                   const int* __restrict__ tlab,
                                                   const int* __restrict__ pairs,
                                                   float* __restrict__ out,
                                                   int NROWS, int C) {
  const int tid = threadIdx.x;
  __shared__ float s_reg[256];
  __shared__ float s_cls[256];
  __shared__ int   s_acc[256];
  float reg = 0.0f, cls = 0.0f; int acc = 0;
  if (tid < NROWS) {
    int pred = pairs[tid];
    float4 pb = pbox[pred];
    float4 tb = tbox[tid];
    float d0 = pb.x - tb.x, d1 = pb.y - tb.y, d2 = pb.z - tb.z, d3 = pb.w - tb.w;
    float a0 = fabsf(d0), a1 = fabsf(d1), a2 = fabsf(d2), a3 = fabsf(d3);
    float s = 0.0f;
    s += (a0 < 1.0f) ? 0.5f * d0 * d0 : a0 - 0.5f;
    s += (a1 < 1.0f) ? 0.5f * d1 * d1 : a1 - 0.5f;
    s += (a2 < 1.0f) ? 0.5f * d2 * d2 : a2 - 0.5f;
    s += (a3 < 1.0f) ? 0.5f * d3 * d3 : a3 - 0.5f;
    reg = s * 0.25f;

    const float* lg = confs + (long long)pred * C;
    float mx = lg[0]; int am = 0;
    for (int k = 1; k < C; ++k) { float x = lg[k]; if (x > mx) { mx = x; am = k; } }
    double se = 0.0;
    for (int k = 0; k < C; ++k) se += exp((double)(lg[k] - mx));
    int lab = tlab[tid];
    double logp = (double)(lg[lab] - mx) - log(se);
    cls = (float)(-logp);
    acc = (am == lab) ? 1 : 0;
  }
  s_reg[tid] = reg; s_cls[tid] = cls; s_acc[tid] = acc;
  __syncthreads();
  for (int s2 = 128; s2 > 0; s2 >>= 1) {
    if (tid < s2) {
      s_reg[tid] += s_reg[tid + s2];
      s_cls[tid] += s_cls[tid + s2];
      s_acc[tid] += s_acc[tid + s2];
    }
    __syncthreads();
  }
  if (tid == 0) {
    out[0] = s_reg[0] + s_cls[0];
    out[1] = (float)s_acc[0];
  }
}

extern "C" void kernel_launch(void* const* d_in, const int* in_sizes, int n_in,
                              void* d_out, int out_size, void* d_ws, size_t ws_size,
                              hipStream_t stream) {
  const float4* pbox  = (const float4*)d_in[0];
  const float*  confs = (const float*)d_in[1];
  const float4* tbox  = (const float4*)d_in[2];
  const int*    tlab  = (const int*)d_in[3];

  int N = in_sizes[0] / 4;          // 100000 predictions (columns)
  int C = in_sizes[1] / N;          // 81 classes
  int NROWS = in_sizes[2] / 4;      // 128 targets (rows), <=128 supported
  int M = N;

  char* w = (char*)d_ws;
  auto alloc = [&](size_t sz) { char* r = w; w += (sz + 255) & ~(size_t)255; return r; };
  u64* cand  = (u64*)alloc((size_t)NROWS * CAND * sizeof(u64));
  int* ncand = (int*)alloc((size_t)(NROWS * SLICES + 8) * sizeof(int));
  int* pairs = (int*)alloc((size_t)(NROWS + 8) * sizeof(int));

  select_kernel<<<dim3(SLICES, NROWS), SEL_THR, 0, stream>>>(pbox, tbox, cand, ncand, M, NROWS);
  match_kernel<<<1, 64, 0, stream>>>(pbox, tbox, cand, ncand, pairs, M, NROWS);
  loss_kernel<<<1, 256, 0, stream>>>(pbox, confs, tbox, tlab, pairs,
                                     (float*)d_out, NROWS, C);
}

// Round 6
// 415.594 us; speedup vs baseline: 1.4992x; 1.4992x over previous
//
#include <hip/hip_runtime.h>
#include <cstdint>
#include <cstddef>

typedef unsigned long long u64;
typedef unsigned int u32;

#define SLICES 2
#define SCAND 192           // per-slice pool capacity
#define CAND 384            // SLICES * SCAND
#define NSLOT 6             // CAND / 64
#define NBINS 4096
#define SEL_THR 1024
#define SEL_TARGET 128
#define POOLCAP 4096
#define MASKW 3200          // 102400 columns max as bits

// IoU exactly as reference _box_iou, all f32 IEEE ops (bit-exact, absmax=0 rounds 1-5).
__device__ __forceinline__ float iou_f32(float4 p, float4 t, float area_t) {
  float area1 = (p.z - p.x) * (p.w - p.y);
  float ltx = fmaxf(p.x, t.x);
  float lty = fmaxf(p.y, t.y);
  float rbx = fminf(p.z, t.z);
  float rby = fminf(p.w, t.w);
  float wx = fmaxf(rbx - ltx, 0.0f);
  float wy = fmaxf(rby - lty, 0.0f);
  float inter = wx * wy;
  return inter / (area1 + area_t - inter);
}

__device__ __forceinline__ u64 map_cost(double cur) {
  u64 b = (u64)__double_as_longlong(cur);
  if (b == 0x8000000000000000ull) b = 0;                 // canonicalize -0 -> +0
  return (b >> 63) ? ~b : (b | 0x8000000000000000ull);   // order-exact total map
}
__device__ __forceinline__ double unmap_cost(u64 m) {
  u64 b = (m >> 63) ? (m ^ 0x8000000000000000ull) : ~m;
  return __longlong_as_double((long long)b);
}

// Kernel A: per (slice,row). One global pass appends all positive-iou cols to an
// LDS pool (wave-aggregated) + histogram; threshold B = highest bin with
// suffix-count >= 128; filtered pool (superset of per-slice top-128 by iou) is
// written as SoA records (key u64, box float4). Union over slices covers top-128.
__global__ __launch_bounds__(SEL_THR) void select_kernel(const float4* __restrict__ pbox,
                                                         const float4* __restrict__ tbox,
                                                         u64* __restrict__ ckey,
                                                         float4* __restrict__ cbox,
                                                         int* __restrict__ ncand,
                                                         int M, int NROWS) {
  __shared__ u32 s_hist[NBINS];
  __shared__ int s_csum[SEL_THR];
  __shared__ u64 s_pool[POOLCAP];
  __shared__ int s_n, s_n2, s_B;
  const int tid = threadIdx.x;
  const int lane = tid & 63;
  const int slice = blockIdx.x, row = blockIdx.y;
  const int sw = (M + SLICES - 1) / SLICES;
  const int base = slice * sw;
  const int send = min(base + sw, M);
  const float4 tb = tbox[row];
  const float area_t = (tb.z - tb.x) * (tb.w - tb.y);
  u64* orow_key = ckey + (size_t)row * CAND + slice * SCAND;
  float4* orow_box = cbox + (size_t)row * CAND + slice * SCAND;

  for (int b = tid; b < NBINS; b += SEL_THR) s_hist[b] = 0;
  if (tid == 0) { s_n = 0; s_n2 = 0; s_B = 0; }
  __syncthreads();

  // pass 1: pool-append positives (ballot-aggregated) + histogram
  const u64 lowmask = (1ull << lane) - 1ull;
  const int iters = (sw + SEL_THR - 1) / SEL_THR;
  for (int it = 0; it < iters; ++it) {
    int j = base + it * SEL_THR + tid;
    bool inr = (j < send);
    float io = -1.0f;
    if (inr) io = iou_f32(pbox[j], tb, area_t);
    bool pos = inr && (io > 0.0f);
    u64 pm = __ballot(pos);
    int wn = (int)__popcll(pm);
    if (wn) {
      int wb = 0;
      if (lane == 0) wb = atomicAdd(&s_n, wn);
      wb = __shfl(wb, 0);
      if (pos) {
        int idx = wb + (int)__popcll(pm & lowmask);
        if (idx < POOLCAP) s_pool[idx] = ((u64)__float_as_uint(io) << 32) | (u32)j;
        atomicAdd(&s_hist[__float_as_uint(io) >> 18], 1u);
      }
    }
  }
  __syncthreads();
  const int np = s_n;

  {
    int b0 = tid * 4;
    s_csum[tid] = (int)(s_hist[b0] + s_hist[b0 + 1] + s_hist[b0 + 2] + s_hist[b0 + 3]);
  }
  __syncthreads();

  if (tid < 64) {                       // wave 0: descending suffix scan for threshold
    if (np >= SEL_TARGET) {
      int R = 0; bool found = false;
      for (int ch = SEL_THR / 64 - 1; ch >= 0 && !found; --ch) {
        int cum = s_csum[ch * 64 + tid];
        for (int off = 1; off < 64; off <<= 1) {
          int o = __shfl_down(cum, off);
          if (tid + off < 64) cum += o;
        }
        int chunksum = __shfl(cum, 0);
        if (R + chunksum >= SEL_TARGET) {
          u64 m = __ballot(R + cum >= SEL_TARGET);
          int l = 63 - __clzll(m);                    // highest lane with suffix >= target
          int R2 = R + ((l < 63) ? __shfl(cum, l + 1) : 0);
          if (tid == 0) {
            int bb = (ch * 64 + l) * 4;
            int B2 = bb;
            for (int b = bb + 3; b >= bb; --b) {
              R2 += (int)s_hist[b];
              if (R2 >= SEL_TARGET) { B2 = b; break; }
            }
            s_B = B2;
          }
          found = true;
        } else R += chunksum;
      }
    }
  }
  __syncthreads();
  const int B = s_B;

  if (np >= SEL_TARGET) {
    if (np <= POOLCAP) {
      // filter the LDS pool (typical: ~2500 entries)
      for (int t = tid; t < np; t += SEL_THR) {
        u64 k = s_pool[t];
        if ((u32)(k >> 50) >= (u32)B) {
          int pos = atomicAdd(&s_n2, 1);
          if (pos < SCAND) { orow_key[pos] = k; orow_box[pos] = pbox[(u32)k]; }
        }
      }
    } else {
      // overflow fallback: re-scan global range with threshold
      for (int j = base + tid; j < send; j += SEL_THR) {
        float io = iou_f32(pbox[j], tb, area_t);
        if (io > 0.0f && (int)(__float_as_uint(io) >> 18) >= B) {
          int pos = atomicAdd(&s_n2, 1);
          if (pos < SCAND) {
            orow_key[pos] = ((u64)__float_as_uint(io) << 32) | (u32)j;
            orow_box[pos] = pbox[j];
          }
        }
      }
    }
    __syncthreads();
  } else {
    // all positives + zero-fill with first (128-np) zero-iou cols ascending
    for (int t = tid; t < np; t += SEL_THR) {
      u64 k = s_pool[t];
      int pos = atomicAdd(&s_n2, 1);
      if (pos < SCAND) { orow_key[pos] = k; orow_box[pos] = pbox[(u32)k]; }
    }
    __syncthreads();
    if (tid < 64) {
      int need = SEL_TARGET - np, got = 0;
      int base_n = s_n2;
      for (int b2 = base; b2 < send && got < need; b2 += 64) {
        int j = b2 + tid;
        float io = (j < send) ? iou_f32(pbox[j], tb, area_t) : -1.0f;
        bool z = (j < send) && (io == 0.0f);
        u64 zm = __ballot(z);
        int rank = (int)__popcll(zm & ((1ull << tid) - 1ull));
        if (z && rank < need - got) {
          int pos = base_n + got + rank;
          if (pos < SCAND) { orow_key[pos] = (u64)(u32)j; orow_box[pos] = pbox[j]; }
        }
        int zn = (int)__popcll(zm); if (zn > need - got) zn = need - got;
        got += zn;
      }
      if (tid == 0) s_n2 = base_n + got;
    }
    __syncthreads();
  }
  if (tid == 0) ncand[row * SLICES + slice] = min(s_n2, SCAND);
}

#define DPP_STEP(CTRL) do { \
  u32 ohi = (u32)__builtin_amdgcn_update_dpp((int)0xFFFFFFFF, (int)khi, (CTRL), 0xF, 0xF, false); \
  u32 olo = (u32)__builtin_amdgcn_update_dpp((int)0xFFFFFFFF, (int)klo, (CTRL), 0xF, 0xF, false); \
  int ocl =      __builtin_amdgcn_update_dpp((int)0x7FFFFFFF, kcol,     (CTRL), 0xF, 0xF, false); \
  bool lt = (ohi < khi) || (ohi == khi && ((olo < klo) || (olo == klo && ocl < kcol))); \
  if (lt) { khi = ohi; klo = olo; kcol = ocl; } \
} while (0)

#define DECODE(NC0n, NC1n) do {                                                       \
  _Pragma("unroll")                                                                    \
  for (int s = 0; s < NSLOT; ++s) {                                                    \
    int idx = (s << 6) + lane;                                                         \
    int lim = (idx < SCAND) ? (NC0n) : (NC1n);                                         \
    int within = (idx < SCAND) ? idx : idx - SCAND;                                    \
    if (within < lim) {                                                                \
      c[s] = (int)(u32)tk[s];                                                          \
      io[s] = __uint_as_float((u32)(tk[s] >> 32));                                     \
    } else c[s] = -1;                                                                  \
  }                                                                                    \
  _Pragma("unroll")                                                                    \
  for (int s = 0; s < NSLOT; ++s)                                                      \
    if (c[s] >= 0 && ((s_mask[(u32)c[s] >> 5] >> ((u32)c[s] & 31u)) & 1u)) c[s] = -1;  \
} while (0)

#define STAGE_ROW(r) do {                                                              \
  _Pragma("unroll")                                                                    \
  for (int s = 0; s < NSLOT; ++s) { tk[s] = pk1[s]; cb[s] = pb1[s];                    \
                                    pk1[s] = pk2[s]; pb1[s] = pb2[s]; }                \
  ncc0 = np10; ncc1 = np11; np10 = np20; np11 = np21;                                  \
  int nr2 = ((r) + 2 <= NROWS) ? (r) + 2 : NROWS;                                      \
  const u64* kp = ckey + (size_t)(nr2 - 1) * CAND;                                     \
  const float4* bp = cbox + (size_t)(nr2 - 1) * CAND;                                  \
  _Pragma("unroll")                                                                    \
  for (int s = 0; s < NSLOT; ++s) { pk2[s] = kp[(s << 6) + lane];                      \
                                    pb2[s] = bp[(s << 6) + lane]; }                    \
  np20 = ncand[2 * (nr2 - 1)]; np21 = ncand[2 * (nr2 - 1) + 1];                        \
  DECODE(ncc0, ncc1);                                                                  \
  f_a = (lane == (((r) - 1) & 63)) && ((((r) - 1) >> 6) == 0);                         \
  f_b = (lane == (((r) - 1) & 63)) && ((((r) - 1) >> 6) == 1);                         \
  u_i0 = 0.0;                                                                          \
} while (0)

#define STAGE_CHAIN(o) do {                                                            \
  const u64* kp = ckey + (size_t)((o) - 1) * CAND;                                     \
  const float4* bp = cbox + (size_t)((o) - 1) * CAND;                                  \
  _Pragma("unroll")                                                                    \
  for (int s = 0; s < NSLOT; ++s) { tk[s] = kp[(s << 6) + lane];                       \
                                    cb[s] = bp[(s << 6) + lane]; }                     \
  int c0 = ncand[2 * ((o) - 1)], c1 = ncand[2 * ((o) - 1) + 1];                        \
  DECODE(c0, c1);                                                                      \
} while (0)

// Kernel B: the serial buggy-JV matcher, 1 wave, no spills (launch_bounds(64,1)),
// coalesced prefetched candidate records, LDS bitmask for owned-exclusion.
// Invariants: visited => owned; v!=0 => owned; ownership frozen during a search.
__global__ __launch_bounds__(64, 1) void match_kernel(const float4* __restrict__ tboxg,
                                                      const u64* __restrict__ ckey,
                                                      const float4* __restrict__ cbox,
                                                      const int* __restrict__ ncand,
                                                      int* __restrict__ pairs,
                                                      int M, int NROWS) {
  const int lane = threadIdx.x;
  __shared__ u32 s_mask[MASKW];
  for (int i = lane; i < MASKW; i += 64) s_mask[i] = 0;

  float4 zf = make_float4(0.f, 0.f, 0.f, 0.f);
  float4 tbA = (lane < NROWS) ? tboxg[lane] : zf;
  float4 tbB = (lane + 64 < NROWS) ? tboxg[lane + 64] : zf;

  double u_a = 0.0, u_b = 0.0;          // u[lane+1], u[lane+65]
  int f_a = 0, f_b = 0;                 // in-chain flags
  int oc0 = -1, orow0 = 0, ovis0 = 0; double ov0 = 0.0; float4 ob0 = zf;
  int oc1 = -1, orow1 = 0, ovis1 = 0; double ov1 = 0.0; float4 ob1 = zf;
  int nown = 0;

  int c[NSLOT]; float io[NSLOT]; float4 cb[NSLOT];
  u64 tk[NSLOT];
  u64 pk1[NSLOT], pk2[NSLOT];
  float4 pb1[NSLOT], pb2[NSLOT];
  int ncc0, ncc1, np10, np11, np20, np21;
  int row = 1, i0 = 1;
  double u_i0 = 0.0;
  __syncthreads();

  {   // initial staging: row 1 direct, rows 2,3 prefetched
#pragma unroll
    for (int s = 0; s < NSLOT; ++s) { tk[s] = ckey[(s << 6) + lane]; cb[s] = cbox[(s << 6) + lane]; }
    ncc0 = ncand[0]; ncc1 = ncand[1];
    int r1 = (2 <= NROWS) ? 2 : 1, r2 = (3 <= NROWS) ? 3 : NROWS;
    const u64* kp1 = ckey + (size_t)(r1 - 1) * CAND;
    const float4* bp1 = cbox + (size_t)(r1 - 1) * CAND;
#pragma unroll
    for (int s = 0; s < NSLOT; ++s) { pk1[s] = kp1[(s << 6) + lane]; pb1[s] = bp1[(s << 6) + lane]; }
    np10 = ncand[2 * (r1 - 1)]; np11 = ncand[2 * (r1 - 1) + 1];
    const u64* kp2 = ckey + (size_t)(r2 - 1) * CAND;
    const float4* bp2 = cbox + (size_t)(r2 - 1) * CAND;
#pragma unroll
    for (int s = 0; s < NSLOT; ++s) { pk2[s] = kp2[(s << 6) + lane]; pb2[s] = bp2[(s << 6) + lane]; }
    np20 = ncand[2 * (r2 - 1)]; np21 = ncand[2 * (r2 - 1) + 1];
    DECODE(ncc0, ncc1);
    f_a = (lane == 0); f_b = 0;
    u_i0 = 0.0;
  }

  for (int guard = 0; guard < 5000; ++guard) {
    // ---- fresh-slot eval: pure registers (v==0, never visited) ----
    u32 bhi = 0xFFFFFFFFu, blo = 0xFFFFFFFFu; int bcol = 0x7fffffff; int bsl = 15;
#pragma unroll
    for (int s = 0; s < NSLOT; ++s) {
      if (c[s] < 0) continue;
      double cur = (-(double)io[s]) - u_i0;          // == ((-io)-u)-0.0 bitwise
      u64 mk = map_cost(cur);
      u32 hi = (u32)(mk >> 32), lo = (u32)mk;
      bool t = (hi < bhi) || (hi == bhi && ((lo < blo) || (lo == blo && c[s] < bcol)));
      if (t) { bhi = hi; blo = lo; bcol = c[s]; bsl = s; }
    }
    // ---- owned eval: registers + readlane'd target box ----
    {
      int li = (i0 - 1) & 63, hb = (i0 - 1) >> 6;
      float tx = __int_as_float(hb ? __builtin_amdgcn_readlane(__float_as_int(tbB.x), li)
                                   : __builtin_amdgcn_readlane(__float_as_int(tbA.x), li));
      float ty = __int_as_float(hb ? __builtin_amdgcn_readlane(__float_as_int(tbB.y), li)
                                   : __builtin_amdgcn_readlane(__float_as_int(tbA.y), li));
      float tz = __int_as_float(hb ? __builtin_amdgcn_readlane(__float_as_int(tbB.z), li)
                                   : __builtin_amdgcn_readlane(__float_as_int(tbA.z), li));
      float tw = __int_as_float(hb ? __builtin_amdgcn_readlane(__float_as_int(tbB.w), li)
                                   : __builtin_amdgcn_readlane(__float_as_int(tbA.w), li));
      float4 tbi = make_float4(tx, ty, tz, tw);
      float ati = (tz - tx) * (tw - ty);
      if (oc0 >= 0 && ovis0 != row) {
        float io2 = iou_f32(ob0, tbi, ati);
        double cur = ((-(double)io2) - u_i0) - ov0;
        u64 mk = map_cost(cur);
        u32 hi = (u32)(mk >> 32), lo = (u32)mk;
        bool t = (hi < bhi) || (hi == bhi && ((lo < blo) || (lo == blo && oc0 < bcol)));
        if (t) { bhi = hi; blo = lo; bcol = oc0; bsl = 6; }
      }
      if (oc1 >= 0 && ovis1 != row) {
        float io2 = iou_f32(ob1, tbi, ati);
        double cur = ((-(double)io2) - u_i0) - ov1;
        u64 mk = map_cost(cur);
        u32 hi = (u32)(mk >> 32), lo = (u32)mk;
        bool t = (hi < bhi) || (hi == bhi && ((lo < blo) || (lo == blo && oc1 < bcol)));
        if (t) { bhi = hi; blo = lo; bcol = oc1; bsl = 7; }
      }
    }
    // ---- 64-lane argmin via DPP (VALU only) ----
    u32 khi = bhi, klo = blo; int kcol = bcol;
    DPP_STEP(0x111); DPP_STEP(0x112); DPP_STEP(0x114); DPP_STEP(0x118);
    DPP_STEP(0x142); DPP_STEP(0x143);
    u32 rhi = (u32)__builtin_amdgcn_readlane((int)khi, 63);
    u32 rlo = (u32)__builtin_amdgcn_readlane((int)klo, 63);
    int jc = __builtin_amdgcn_readlane(kcol, 63);
    const double delta = unmap_cost(((u64)rhi << 32) | (u64)rlo);

    // ---- updates: u[p[used]] += delta ; v[used] -= delta (pre-append used set) ----
    if (f_a) u_a += delta;
    if (f_b) u_b += delta;
    u_i0 += delta;
    if (oc0 >= 0 && ovis0 == row) ov0 -= delta;
    if (oc1 >= 0 && ovis1 == row) ov1 -= delta;

    // ---- winner lane (unique claimant; prefer owned on exact tie for safety) ----
    bool eq = (bhi == rhi) && (blo == rlo) && (bcol == jc);
    u64 wown = __ballot(eq && bsl >= 6);
    u64 wany = __ballot(eq);
    u64 wm = wown ? wown : wany;
    int L = (int)__ffsll((long long)wm) - 1;
    L = __builtin_amdgcn_readfirstlane(L);
    int s_w = __builtin_amdgcn_readlane(bsl, L);

    if (s_w >= 6) {
      // chain to owner row
      int o = __builtin_amdgcn_readlane((s_w == 6) ? orow0 : orow1, L);
      o = __builtin_amdgcn_readfirstlane(o);
      if (lane == L) { if (s_w == 6) ovis0 = row; else ovis1 = row; }
      int ol = (o - 1) & 63, oh = (o - 1) >> 6;
      if (lane == ol) { if (oh == 0) f_a = 1; else f_b = 1; }
      double uo = oh ? u_b : u_a;
      int uhi = __builtin_amdgcn_readlane(__double2hiint(uo), ol);
      int ulo = __builtin_amdgcn_readlane(__double2loint(uo), ol);
      u_i0 = __hiloint2double(uhi, ulo);
      i0 = o;
      STAGE_CHAIN(o);
    } else {
      // augment: way==0 collapses to single assignment p[jc]=row
      if (lane == 0) {
        pairs[row - 1] = jc;
        atomicOr(&s_mask[(u32)jc >> 5], 1u << ((u32)jc & 31u));
      }
      float4 wb = cb[0];
      if (bsl == 1) wb = cb[1];
      if (bsl == 2) wb = cb[2];
      if (bsl == 3) wb = cb[3];
      if (bsl == 4) wb = cb[4];
      if (bsl == 5) wb = cb[5];
      float4 nb;
      nb.x = __int_as_float(__builtin_amdgcn_readlane(__float_as_int(wb.x), L));
      nb.y = __int_as_float(__builtin_amdgcn_readlane(__float_as_int(wb.y), L));
      nb.z = __int_as_float(__builtin_amdgcn_readlane(__float_as_int(wb.z), L));
      nb.w = __int_as_float(__builtin_amdgcn_readlane(__float_as_int(wb.w), L));
      int ne = nown, nl = ne & 63, nh = ne >> 6;
      if (lane == nl) {
        if (nh == 0) { oc0 = jc; orow0 = row; ovis0 = 0; ov0 = 0.0; ob0 = nb; }
        else         { oc1 = jc; orow1 = row; ovis1 = 0; ov1 = 0.0; ob1 = nb; }
      }
      nown = ne + 1;
      if (row == NROWS) break;
      ++row; i0 = row;
      __builtin_amdgcn_wave_barrier();
      STAGE_ROW(row);
    }
  }
}

__global__ __launch_bounds__(256) void loss_kernel(const float4* __restrict__ pbox,
                                                   const float* __restrict__ confs,
                                                   const float4* __restrict__ tbox,
                                                   const int* __restrict__ tlab,
                                                   const int* __restrict__ pairs,
                                                   float* __restrict__ out,
                                                   int NROWS, int C) {
  const int tid = threadIdx.x;
  __shared__ float s_reg[256];
  __shared__ float s_cls[256];
  __shared__ int   s_acc[256];
  float reg = 0.0f, cls = 0.0f; int acc = 0;
  if (tid < NROWS) {
    int pred = pairs[tid];
    float4 pb = pbox[pred];
    float4 tb = tbox[tid];
    float d0 = pb.x - tb.x, d1 = pb.y - tb.y, d2 = pb.z - tb.z, d3 = pb.w - tb.w;
    float a0 = fabsf(d0), a1 = fabsf(d1), a2 = fabsf(d2), a3 = fabsf(d3);
    float s = 0.0f;
    s += (a0 < 1.0f) ? 0.5f * d0 * d0 : a0 - 0.5f;
    s += (a1 < 1.0f) ? 0.5f * d1 * d1 : a1 - 0.5f;
    s += (a2 < 1.0f) ? 0.5f * d2 * d2 : a2 - 0.5f;
    s += (a3 < 1.0f) ? 0.5f * d3 * d3 : a3 - 0.5f;
    reg = s * 0.25f;

    const float* lg = confs + (long long)pred * C;
    float mx = lg[0]; int am = 0;
    for (int k = 1; k < C; ++k) { float x = lg[k]; if (x > mx) { mx = x; am = k; } }
    double se = 0.0;
    for (int k = 0; k < C; ++k) se += exp((double)(lg[k] - mx));
    int lab = tlab[tid];
    double logp = (double)(lg[lab] - mx) - log(se);
    cls = (float)(-logp);
    acc = (am == lab) ? 1 : 0;
  }
  s_reg[tid] = reg; s_cls[tid] = cls; s_acc[tid] = acc;
  __syncthreads();
  for (int s2 = 128; s2 > 0; s2 >>= 1) {
    if (tid < s2) {
      s_reg[tid] += s_reg[tid + s2];
      s_cls[tid] += s_cls[tid + s2];
      s_acc[tid] += s_acc[tid + s2];
    }
    __syncthreads();
  }
  if (tid == 0) {
    out[0] = s_reg[0] + s_cls[0];
    out[1] = (float)s_acc[0];
  }
}

extern "C" void kernel_launch(void* const* d_in, const int* in_sizes, int n_in,
                              void* d_out, int out_size, void* d_ws, size_t ws_size,
                              hipStream_t stream) {
  const float4* pbox  = (const float4*)d_in[0];
  const float*  confs = (const float*)d_in[1];
  const float4* tbox  = (const float4*)d_in[2];
  const int*    tlab  = (const int*)d_in[3];

  int N = in_sizes[0] / 4;          // 100000 predictions (columns)
  int C = in_sizes[1] / N;          // 81 classes
  int NROWS = in_sizes[2] / 4;      // 128 targets (rows), <=128 supported
  int M = N;

  char* w = (char*)d_ws;
  auto alloc = [&](size_t sz) { char* r = w; w += (sz + 255) & ~(size_t)255; return r; };
  u64*    ckey  = (u64*)   alloc((size_t)NROWS * CAND * sizeof(u64));
  float4* cbox  = (float4*)alloc((size_t)NROWS * CAND * sizeof(float4));
  int*    ncand = (int*)   alloc((size_t)(NROWS * SLICES + 8) * sizeof(int));
  int*    pairs = (int*)   alloc((size_t)(NROWS + 8) * sizeof(int));

  select_kernel<<<dim3(SLICES, NROWS), SEL_THR, 0, stream>>>(pbox, tbox, ckey, cbox, ncand, M, NROWS);
  match_kernel<<<1, 64, 0, stream>>>(tbox, ckey, cbox, ncand, pairs, M, NROWS);
  loss_kernel<<<1, 256, 0, stream>>>(pbox, confs, tbox, tlab, pairs,
                                     (float*)d_out, NROWS, C);
}

// Round 7
// 311.904 us; speedup vs baseline: 1.9977x; 1.3324x over previous
//
#include <hip/hip_runtime.h>
#include <cstdint>
#include <cstddef>

typedef unsigned long long u64;
typedef unsigned int u32;

#define SLICES 2
#define SCAND 192           // per-slice pool capacity
#define CAND 384            // SLICES * SCAND
#define NSLOT 6             // CAND / 64
#define NBINS 4096
#define SEL_THR 1024
#define SEL_TARGET 128
#define POOLCAP 4096
#define MASKW 3200          // 102400 columns max as bits
#define SENTKEY 0xFF80000000000000ull   // io = -inf (f32), col = 0 -> cost +inf, never wins

// IoU exactly as reference _box_iou, all f32 IEEE ops (bit-exact, absmax=0 rounds 1-6).
__device__ __forceinline__ float iou_f32(float4 p, float4 t, float area_t) {
  float area1 = (p.z - p.x) * (p.w - p.y);
  float ltx = fmaxf(p.x, t.x);
  float lty = fmaxf(p.y, t.y);
  float rbx = fminf(p.z, t.z);
  float rby = fminf(p.w, t.w);
  float wx = fmaxf(rbx - ltx, 0.0f);
  float wy = fmaxf(rby - lty, 0.0f);
  float inter = wx * wy;
  return inter / (area1 + area_t - inter);
}

__device__ __forceinline__ u64 map_cost(double cur) {
  u64 b = (u64)__double_as_longlong(cur);
  if (b == 0x8000000000000000ull) b = 0;                 // canonicalize -0 -> +0
  return (b >> 63) ? ~b : (b | 0x8000000000000000ull);   // order-exact total map
}
__device__ __forceinline__ double unmap_cost(u64 m) {
  u64 b = (m >> 63) ? (m ^ 0x8000000000000000ull) : ~m;
  return __longlong_as_double((long long)b);
}

// Kernel A: per (slice,row). One global pass appends all positive-iou cols to an
// LDS pool (ballot-aggregated) + histogram; threshold B = highest bin with
// suffix-count >= 128; filtered pool (superset of per-slice top-128 by iou) is
// written as key records; tail padded with SENTKEY. Union over slices ⊇ top-128.
__global__ __launch_bounds__(SEL_THR) void select_kernel(const float4* __restrict__ pbox,
                                                         const float4* __restrict__ tbox,
                                                         u64* __restrict__ ckey,
                                                         int M, int NROWS) {
  __shared__ u32 s_hist[NBINS];
  __shared__ int s_csum[SEL_THR];
  __shared__ u64 s_pool[POOLCAP];
  __shared__ int s_n, s_n2, s_B;
  const int tid = threadIdx.x;
  const int lane = tid & 63;
  const int slice = blockIdx.x, row = blockIdx.y;
  const int sw = (M + SLICES - 1) / SLICES;
  const int base = slice * sw;
  const int send = min(base + sw, M);
  const float4 tb = tbox[row];
  const float area_t = (tb.z - tb.x) * (tb.w - tb.y);
  u64* orow_key = ckey + (size_t)row * CAND + slice * SCAND;

  for (int b = tid; b < NBINS; b += SEL_THR) s_hist[b] = 0;
  if (tid == 0) { s_n = 0; s_n2 = 0; s_B = 0; }
  __syncthreads();

  // pass 1: pool-append positives (ballot-aggregated) + histogram
  const u64 lowmask = (1ull << lane) - 1ull;
  const int iters = (sw + SEL_THR - 1) / SEL_THR;
  for (int it = 0; it < iters; ++it) {
    int j = base + it * SEL_THR + tid;
    bool inr = (j < send);
    float io = -1.0f;
    if (inr) io = iou_f32(pbox[j], tb, area_t);
    bool pos = inr && (io > 0.0f);
    u64 pm = __ballot(pos);
    int wn = (int)__popcll(pm);
    if (wn) {
      int wb = 0;
      if (lane == 0) wb = atomicAdd(&s_n, wn);
      wb = __shfl(wb, 0);
      if (pos) {
        int idx = wb + (int)__popcll(pm & lowmask);
        if (idx < POOLCAP) s_pool[idx] = ((u64)__float_as_uint(io) << 32) | (u32)j;
        atomicAdd(&s_hist[__float_as_uint(io) >> 18], 1u);
      }
    }
  }
  __syncthreads();
  const int np = s_n;

  {
    int b0 = tid * 4;
    s_csum[tid] = (int)(s_hist[b0] + s_hist[b0 + 1] + s_hist[b0 + 2] + s_hist[b0 + 3]);
  }
  __syncthreads();

  if (tid < 64) {                       // wave 0: descending suffix scan for threshold
    if (np >= SEL_TARGET) {
      int R = 0; bool found = false;
      for (int ch = SEL_THR / 64 - 1; ch >= 0 && !found; --ch) {
        int cum = s_csum[ch * 64 + tid];
        for (int off = 1; off < 64; off <<= 1) {
          int o = __shfl_down(cum, off);
          if (tid + off < 64) cum += o;
        }
        int chunksum = __shfl(cum, 0);
        if (R + chunksum >= SEL_TARGET) {
          u64 m = __ballot(R + cum >= SEL_TARGET);
          int l = 63 - __clzll(m);                    // highest lane with suffix >= target
          int R2 = R + ((l < 63) ? __shfl(cum, l + 1) : 0);
          if (tid == 0) {
            int bb = (ch * 64 + l) * 4;
            int B2 = bb;
            for (int b = bb + 3; b >= bb; --b) {
              R2 += (int)s_hist[b];
              if (R2 >= SEL_TARGET) { B2 = b; break; }
            }
            s_B = B2;
          }
          found = true;
        } else R += chunksum;
      }
    }
  }
  __syncthreads();
  const int B = s_B;

  if (np >= SEL_TARGET) {
    if (np <= POOLCAP) {
      // filter the LDS pool (typical: ~2500 entries)
      for (int t = tid; t < np; t += SEL_THR) {
        u64 k = s_pool[t];
        if ((u32)(k >> 50) >= (u32)B) {
          int pos = atomicAdd(&s_n2, 1);
          if (pos < SCAND) orow_key[pos] = k;
        }
      }
    } else {
      // overflow fallback: re-scan global range with threshold
      for (int j = base + tid; j < send; j += SEL_THR) {
        float io = iou_f32(pbox[j], tb, area_t);
        if (io > 0.0f && (int)(__float_as_uint(io) >> 18) >= B) {
          int pos = atomicAdd(&s_n2, 1);
          if (pos < SCAND) orow_key[pos] = ((u64)__float_as_uint(io) << 32) | (u32)j;
        }
      }
    }
    __syncthreads();
  } else {
    // all positives + zero-fill with first (128-np) zero-iou cols ascending
    for (int t = tid; t < np; t += SEL_THR) {
      u64 k = s_pool[t];
      int pos = atomicAdd(&s_n2, 1);
      if (pos < SCAND) orow_key[pos] = k;
    }
    __syncthreads();
    if (tid < 64) {
      int need = SEL_TARGET - np, got = 0;
      int base_n = s_n2;
      for (int b2 = base; b2 < send && got < need; b2 += 64) {
        int j = b2 + tid;
        float io = (j < send) ? iou_f32(pbox[j], tb, area_t) : -1.0f;
        bool z = (j < send) && (io == 0.0f);
        u64 zm = __ballot(z);
        int rank = (int)__popcll(zm & ((1ull << tid) - 1ull));
        if (z && rank < need - got) {
          int pos = base_n + got + rank;
          if (pos < SCAND) orow_key[pos] = (u64)(u32)j;
        }
        int zn = (int)__popcll(zm); if (zn > need - got) zn = need - got;
        got += zn;
      }
      if (tid == 0) s_n2 = base_n + got;
    }
    __syncthreads();
  }
  int n = min(s_n2, SCAND);
  for (int t2 = n + tid; t2 < SCAND; t2 += SEL_THR) orow_key[t2] = SENTKEY;
}

#define DPP_STEP(CTRL) do { \
  u32 ohi = (u32)__builtin_amdgcn_update_dpp((int)0xFFFFFFFF, (int)khi, (CTRL), 0xF, 0xF, false); \
  u32 olo = (u32)__builtin_amdgcn_update_dpp((int)0xFFFFFFFF, (int)klo, (CTRL), 0xF, 0xF, false); \
  int ocl =      __builtin_amdgcn_update_dpp((int)0x7FFFFFFF, kcol,     (CTRL), 0xF, 0xF, false); \
  bool lt = (ohi < khi) || (ohi == khi && ((olo < klo) || (olo == klo && ocl < kcol))); \
  if (lt) { khi = ohi; klo = olo; kcol = ocl; } \
} while (0)

#define DECODE() do {                                                                  \
  _Pragma("unroll")                                                                    \
  for (int s = 0; s < NSLOT; ++s) {                                                    \
    u32 cw = (u32)tk[s];                                                               \
    if ((s_mask[cw >> 5] >> (cw & 31u)) & 1u) tk[s] = SENTKEY;                         \
  }                                                                                    \
} while (0)

#define STAGE_ROW(r) do {                                                              \
  _Pragma("unroll")                                                                    \
  for (int s = 0; s < NSLOT; ++s) { tk[s] = pk1[s]; pk1[s] = pk2[s]; }                 \
  int nr2 = ((r) + 2 <= NROWS) ? (r) + 2 : NROWS;                                      \
  const u64* kp = ckey + (size_t)(nr2 - 1) * CAND;                                     \
  _Pragma("unroll")                                                                    \
  for (int s = 0; s < NSLOT; ++s) pk2[s] = kp[(s << 6) + lane];                        \
  DECODE();                                                                            \
  f_a = (lane == (((r) - 1) & 63)) && ((((r) - 1) >> 6) == 0);                         \
  f_b = (lane == (((r) - 1) & 63)) && ((((r) - 1) >> 6) == 1);                         \
  u_i0 = 0.0;                                                                          \
} while (0)

#define STAGE_CHAIN(o) do {                                                            \
  const u64* kp = ckey + (size_t)((o) - 1) * CAND;                                     \
  _Pragma("unroll")                                                                    \
  for (int s = 0; s < NSLOT; ++s) tk[s] = kp[(s << 6) + lane];                         \
  DECODE();                                                                            \
} while (0)

// Kernel B: the serial buggy-JV matcher, 1 wave, spill-free (~90 VGPR state).
// Invariants: visited => owned; v!=0 => owned; ownership frozen during a search.
// Fresh candidates: cost = (-io) - u_i0 (bitwise == reference ((-io)-u)-0.0).
__global__ __launch_bounds__(64, 1) void match_kernel(const float4* __restrict__ pbox,
                                                      const float4* __restrict__ tboxg,
                                                      const u64* __restrict__ ckey,
                                                      int* __restrict__ pairs,
                                                      int M, int NROWS) {
  const int lane = threadIdx.x;
  __shared__ u32 s_mask[MASKW];
  for (int i = lane; i < MASKW; i += 64) s_mask[i] = 0;
  __syncthreads();

  float4 zf = make_float4(0.f, 0.f, 0.f, 0.f);
  float4 tbA = (lane < NROWS) ? tboxg[lane] : zf;
  float4 tbB = (lane + 64 < NROWS) ? tboxg[lane + 64] : zf;

  double u_a = 0.0, u_b = 0.0;          // u[lane+1], u[lane+65]
  int f_a = 0, f_b = 0;                 // in-chain flags
  int oc0 = -1, orow0 = 0, ovis0 = 0; double ov0 = 0.0; float4 ob0 = zf;
  int oc1 = -1, orow1 = 0, ovis1 = 0; double ov1 = 0.0; float4 ob1 = zf;
  int nown = 0;

  u64 tk[NSLOT], pk1[NSLOT], pk2[NSLOT];
  int row = 1, i0 = 1;
  double u_i0 = 0.0;

  {   // initial staging: row 1 direct, rows 2,3 prefetched
#pragma unroll
    for (int s = 0; s < NSLOT; ++s) tk[s] = ckey[(s << 6) + lane];
    int r1 = (2 <= NROWS) ? 2 : 1, r2 = (3 <= NROWS) ? 3 : NROWS;
    const u64* kp1 = ckey + (size_t)(r1 - 1) * CAND;
    const u64* kp2 = ckey + (size_t)(r2 - 1) * CAND;
#pragma unroll
    for (int s = 0; s < NSLOT; ++s) { pk1[s] = kp1[(s << 6) + lane]; pk2[s] = kp2[(s << 6) + lane]; }
    DECODE();
    f_a = (lane == 0); f_b = 0;
    u_i0 = 0.0;
  }

  for (int guard = 0; guard < 5000; ++guard) {
    // ---- fresh-slot eval: pure registers (v==0, never visited; SENT -> +inf) ----
    u32 bhi = 0xFFFFFFFFu, blo = 0xFFFFFFFFu; int bcol = 0x7fffffff; int bsl = 15;
#pragma unroll
    for (int s = 0; s < NSLOT; ++s) {
      float iof = __uint_as_float((u32)(tk[s] >> 32));
      int col = (int)(u32)tk[s];
      double cur = (-(double)iof) - u_i0;            // exact reference f64 op order
      u64 mk = map_cost(cur);
      u32 hi = (u32)(mk >> 32), lo = (u32)mk;
      bool t = (hi < bhi) || (hi == bhi && ((lo < blo) || (lo == blo && col < bcol)));
      if (t) { bhi = hi; blo = lo; bcol = col; bsl = s; }
    }
    // ---- owned eval: registers + readlane'd target box ----
    {
      int li = (i0 - 1) & 63, hb = (i0 - 1) >> 6;
      float tx = __int_as_float(hb ? __builtin_amdgcn_readlane(__float_as_int(tbB.x), li)
                                   : __builtin_amdgcn_readlane(__float_as_int(tbA.x), li));
      float ty = __int_as_float(hb ? __builtin_amdgcn_readlane(__float_as_int(tbB.y), li)
                                   : __builtin_amdgcn_readlane(__float_as_int(tbA.y), li));
      float tz = __int_as_float(hb ? __builtin_amdgcn_readlane(__float_as_int(tbB.z), li)
                                   : __builtin_amdgcn_readlane(__float_as_int(tbA.z), li));
      float tw = __int_as_float(hb ? __builtin_amdgcn_readlane(__float_as_int(tbB.w), li)
                                   : __builtin_amdgcn_readlane(__float_as_int(tbA.w), li));
      float4 tbi = make_float4(tx, ty, tz, tw);
      float ati = (tz - tx) * (tw - ty);
      if (oc0 >= 0 && ovis0 != row) {
        float io2 = iou_f32(ob0, tbi, ati);
        double cur = ((-(double)io2) - u_i0) - ov0;
        u64 mk = map_cost(cur);
        u32 hi = (u32)(mk >> 32), lo = (u32)mk;
        bool t = (hi < bhi) || (hi == bhi && ((lo < blo) || (lo == blo && oc0 < bcol)));
        if (t) { bhi = hi; blo = lo; bcol = oc0; bsl = 6; }
      }
      if (oc1 >= 0 && ovis1 != row) {
        float io2 = iou_f32(ob1, tbi, ati);
        double cur = ((-(double)io2) - u_i0) - ov1;
        u64 mk = map_cost(cur);
        u32 hi = (u32)(mk >> 32), lo = (u32)mk;
        bool t = (hi < bhi) || (hi == bhi && ((lo < blo) || (lo == blo && oc1 < bcol)));
        if (t) { bhi = hi; blo = lo; bcol = oc1; bsl = 7; }
      }
    }
    // ---- 64-lane argmin via DPP (VALU only) ----
    u32 khi = bhi, klo = blo; int kcol = bcol;
    DPP_STEP(0x111); DPP_STEP(0x112); DPP_STEP(0x114); DPP_STEP(0x118);
    DPP_STEP(0x142); DPP_STEP(0x143);
    u32 rhi = (u32)__builtin_amdgcn_readlane((int)khi, 63);
    u32 rlo = (u32)__builtin_amdgcn_readlane((int)klo, 63);
    int jc = __builtin_amdgcn_readlane(kcol, 63);
    const double delta = unmap_cost(((u64)rhi << 32) | (u64)rlo);

    // early uniform load of winner box (used only on augment; hides latency)
    float4 wbx = pbox[jc];

    // ---- updates: u[p[used]] += delta ; v[used] -= delta (pre-append used set) ----
    if (f_a) u_a += delta;
    if (f_b) u_b += delta;
    u_i0 += delta;
    if (oc0 >= 0 && ovis0 == row) ov0 -= delta;
    if (oc1 >= 0 && ovis1 == row) ov1 -= delta;

    // ---- winner lane (claimant unique: no duplicate columns across slots) ----
    bool eq = (bhi == rhi) && (blo == rlo) && (bcol == jc);
    u64 wm = __ballot(eq);
    int L = (int)__ffsll((long long)wm) - 1;
    L = __builtin_amdgcn_readfirstlane(L);
    int s_w = __builtin_amdgcn_readlane(bsl, L);

    if (s_w >= 6) {
      // chain to owner row
      int o = __builtin_amdgcn_readlane((s_w == 6) ? orow0 : orow1, L);
      o = __builtin_amdgcn_readfirstlane(o);
      if (lane == L) { if (s_w == 6) ovis0 = row; else ovis1 = row; }
      int ol = (o - 1) & 63, oh = (o - 1) >> 6;
      if (lane == ol) { if (oh == 0) f_a = 1; else f_b = 1; }
      double uo = oh ? u_b : u_a;
      int uhi = __builtin_amdgcn_readlane(__double2hiint(uo), ol);
      int ulo = __builtin_amdgcn_readlane(__double2loint(uo), ol);
      u_i0 = __hiloint2double(uhi, ulo);
      i0 = o;
      STAGE_CHAIN(o);
    } else {
      // augment: way==0 collapses to single assignment p[jc]=row
      if (lane == 0) {
        pairs[row - 1] = jc;
        atomicOr(&s_mask[(u32)jc >> 5], 1u << ((u32)jc & 31u));
      }
      int ne = nown, nl = ne & 63, nh = ne >> 6;
      if (lane == nl) {
        if (nh == 0) { oc0 = jc; orow0 = row; ovis0 = 0; ov0 = 0.0; ob0 = wbx; }
        else         { oc1 = jc; orow1 = row; ovis1 = 0; ov1 = 0.0; ob1 = wbx; }
      }
      nown = ne + 1;
      if (row == NROWS) break;
      ++row; i0 = row;
      asm volatile("s_waitcnt lgkmcnt(0)" ::: "memory");  // order atomicOr vs DECODE reads
      STAGE_ROW(row);
    }
  }
}

__global__ __launch_bounds__(256) void loss_kernel(const float4* __restrict__ pbox,
                                                   const float* __restrict__ confs,
                                                   const float4* __restrict__ tbox,
                                                   const int* __restrict__ tlab,
                                                   const int* __restrict__ pairs,
                                                   float* __restrict__ out,
                                                   int NROWS, int C) {
  const int tid = threadIdx.x;
  __shared__ float s_reg[256];
  __shared__ float s_cls[256];
  __shared__ int   s_acc[256];
  float reg = 0.0f, cls = 0.0f; int acc = 0;
  if (tid < NROWS) {
    int pred = pairs[tid];
    float4 pb = pbox[pred];
    float4 tb = tbox[tid];
    float d0 = pb.x - tb.x, d1 = pb.y - tb.y, d2 = pb.z - tb.z, d3 = pb.w - tb.w;
    float a0 = fabsf(d0), a1 = fabsf(d1), a2 = fabsf(d2), a3 = fabsf(d3);
    float s = 0.0f;
    s += (a0 < 1.0f) ? 0.5f * d0 * d0 : a0 - 0.5f;
    s += (a1 < 1.0f) ? 0.5f * d1 * d1 : a1 - 0.5f;
    s += (a2 < 1.0f) ? 0.5f * d2 * d2 : a2 - 0.5f;
    s += (a3 < 1.0f) ? 0.5f * d3 * d3 : a3 - 0.5f;
    reg = s * 0.25f;

    const float* lg = confs + (long long)pred * C;
    float mx = lg[0]; int am = 0;
    for (int k = 1; k < C; ++k) { float x = lg[k]; if (x > mx) { mx = x; am = k; } }
    double se = 0.0;
    for (int k = 0; k < C; ++k) se += exp((double)(lg[k] - mx));
    int lab = tlab[tid];
    double logp = (double)(lg[lab] - mx) - log(se);
    cls = (float)(-logp);
    acc = (am == lab) ? 1 : 0;
  }
  s_reg[tid] = reg; s_cls[tid] = cls; s_acc[tid] = acc;
  __syncthreads();
  for (int s2 = 128; s2 > 0; s2 >>= 1) {
    if (tid < s2) {
      s_reg[tid] += s_reg[tid + s2];
      s_cls[tid] += s_cls[tid + s2];
      s_acc[tid] += s_acc[tid + s2];
    }
    __syncthreads();
  }
  if (tid == 0) {
    out[0] = s_reg[0] + s_cls[0];
    out[1] = (float)s_acc[0];
  }
}

extern "C" void kernel_launch(void* const* d_in, const int* in_sizes, int n_in,
                              void* d_out, int out_size, void* d_ws, size_t ws_size,
                              hipStream_t stream) {
  const float4* pbox  = (const float4*)d_in[0];
  const float*  confs = (const float*)d_in[1];
  const float4* tbox  = (const float4*)d_in[2];
  const int*    tlab  = (const int*)d_in[3];

  int N = in_sizes[0] / 4;          // 100000 predictions (columns)
  int C = in_sizes[1] / N;          // 81 classes
  int NROWS = in_sizes[2] / 4;      // 128 targets (rows), <=128 supported
  int M = N;

  char* w = (char*)d_ws;
  auto alloc = [&](size_t sz) { char* r = w; w += (sz + 255) & ~(size_t)255; return r; };
  u64* ckey  = (u64*)alloc((size_t)NROWS * CAND * sizeof(u64));
  int* pairs = (int*)alloc((size_t)(NROWS + 8) * sizeof(int));

  select_kernel<<<dim3(SLICES, NROWS), SEL_THR, 0, stream>>>(pbox, tbox, ckey, M, NROWS);
  match_kernel<<<1, 64, 0, stream>>>(pbox, tbox, ckey, pairs, M, NROWS);
  loss_kernel<<<1, 256, 0, stream>>>(pbox, confs, tbox, tlab, pairs,
                                     (float*)d_out, NROWS, C);
}

// Round 8
// 309.781 us; speedup vs baseline: 2.0113x; 1.0069x over previous
//
#include <hip/hip_runtime.h>
#include <cstdint>
#include <cstddef>

typedef unsigned long long u64;
typedef unsigned int u32;

#define SLICES 2
#define SCAND 192           // per-slice pool capacity
#define CAND 384            // SLICES * SCAND
#define NSLOT 6             // CAND / 64
#define NBINS 4096
#define SEL_THR 1024
#define SEL_TARGET 128
#define POOLCAP 4096
#define MASKW 3200          // 102400 columns max as bits

// IoU exactly as reference _box_iou, all f32 IEEE ops (bit-exact, absmax=0 rounds 1-7).
__device__ __forceinline__ float iou_f32(float4 p, float4 t, float area_t) {
  float area1 = (p.z - p.x) * (p.w - p.y);
  float ltx = fmaxf(p.x, t.x);
  float lty = fmaxf(p.y, t.y);
  float rbx = fminf(p.z, t.z);
  float rby = fminf(p.w, t.w);
  float wx = fmaxf(rbx - ltx, 0.0f);
  float wy = fmaxf(rby - lty, 0.0f);
  float inter = wx * wy;
  return inter / (area1 + area_t - inter);
}

__device__ __forceinline__ u64 map_cost(double cur) {
  u64 b = (u64)__double_as_longlong(cur);
  if (b == 0x8000000000000000ull) b = 0;                 // canonicalize -0 -> +0
  return (b >> 63) ? ~b : (b | 0x8000000000000000ull);   // order-exact total map
}
__device__ __forceinline__ double unmap_cost(u64 m) {
  u64 b = (m >> 63) ? (m ^ 0x8000000000000000ull) : ~m;
  return __longlong_as_double((long long)b);
}

// Key encoding: (io_bits << 32) | (0xFFFFFFFF - col). Raw u64 max = (io desc, col asc).
// Padding = 0 (io=+0, col=0xFFFFFFFF invalid) — never beats a legit entry.

// Kernel A: per (slice,row). One global pass appends all positive-iou cols to an
// LDS pool (ballot-aggregated) + histogram; threshold B = highest bin with
// suffix-count >= 128; filtered pool (superset of per-slice top-128 by iou,
// all boundary ties included) written as keys; tail padded with 0.
__global__ __launch_bounds__(SEL_THR) void select_kernel(const float4* __restrict__ pbox,
                                                         const float4* __restrict__ tbox,
                                                         u64* __restrict__ ckey,
                                                         int M, int NROWS) {
  __shared__ u32 s_hist[NBINS];
  __shared__ int s_csum[SEL_THR];
  __shared__ u64 s_pool[POOLCAP];
  __shared__ int s_n, s_n2, s_B;
  const int tid = threadIdx.x;
  const int lane = tid & 63;
  const int slice = blockIdx.x, row = blockIdx.y;
  const int sw = (M + SLICES - 1) / SLICES;
  const int base = slice * sw;
  const int send = min(base + sw, M);
  const float4 tb = tbox[row];
  const float area_t = (tb.z - tb.x) * (tb.w - tb.y);
  u64* orow_key = ckey + (size_t)row * CAND + slice * SCAND;

  for (int b = tid; b < NBINS; b += SEL_THR) s_hist[b] = 0;
  if (tid == 0) { s_n = 0; s_n2 = 0; s_B = 0; }
  __syncthreads();

  // pass 1: pool-append positives (ballot-aggregated) + histogram
  const u64 lowmask = (1ull << lane) - 1ull;
  const int iters = (sw + SEL_THR - 1) / SEL_THR;
  for (int it = 0; it < iters; ++it) {
    int j = base + it * SEL_THR + tid;
    bool inr = (j < send);
    float io = -1.0f;
    if (inr) io = iou_f32(pbox[j], tb, area_t);
    bool pos = inr && (io > 0.0f);
    u64 pm = __ballot(pos);
    int wn = (int)__popcll(pm);
    if (wn) {
      int wb = 0;
      if (lane == 0) wb = atomicAdd(&s_n, wn);
      wb = __shfl(wb, 0);
      if (pos) {
        int idx = wb + (int)__popcll(pm & lowmask);
        if (idx < POOLCAP) s_pool[idx] = ((u64)__float_as_uint(io) << 32) | (u64)(0xFFFFFFFFu - (u32)j);
        atomicAdd(&s_hist[__float_as_uint(io) >> 18], 1u);
      }
    }
  }
  __syncthreads();
  const int np = s_n;

  {
    int b0 = tid * 4;
    s_csum[tid] = (int)(s_hist[b0] + s_hist[b0 + 1] + s_hist[b0 + 2] + s_hist[b0 + 3]);
  }
  __syncthreads();

  if (tid < 64) {                       // wave 0: descending suffix scan for threshold
    if (np >= SEL_TARGET) {
      int R = 0; bool found = false;
      for (int ch = SEL_THR / 64 - 1; ch >= 0 && !found; --ch) {
        int cum = s_csum[ch * 64 + tid];
        for (int off = 1; off < 64; off <<= 1) {
          int o = __shfl_down(cum, off);
          if (tid + off < 64) cum += o;
        }
        int chunksum = __shfl(cum, 0);
        if (R + chunksum >= SEL_TARGET) {
          u64 m = __ballot(R + cum >= SEL_TARGET);
          int l = 63 - __clzll(m);                    // highest lane with suffix >= target
          int R2 = R + ((l < 63) ? __shfl(cum, l + 1) : 0);
          if (tid == 0) {
            int bb = (ch * 64 + l) * 4;
            int B2 = bb;
            for (int b = bb + 3; b >= bb; --b) {
              R2 += (int)s_hist[b];
              if (R2 >= SEL_TARGET) { B2 = b; break; }
            }
            s_B = B2;
          }
          found = true;
        } else R += chunksum;
      }
    }
  }
  __syncthreads();
  const int B = s_B;

  if (np >= SEL_TARGET) {
    if (np <= POOLCAP) {
      for (int t = tid; t < np; t += SEL_THR) {
        u64 k = s_pool[t];
        if ((u32)(k >> 50) >= (u32)B) {
          int pos = atomicAdd(&s_n2, 1);
          if (pos < SCAND) orow_key[pos] = k;
        }
      }
    } else {
      for (int j = base + tid; j < send; j += SEL_THR) {
        float io = iou_f32(pbox[j], tb, area_t);
        if (io > 0.0f && (int)(__float_as_uint(io) >> 18) >= B) {
          int pos = atomicAdd(&s_n2, 1);
          if (pos < SCAND) orow_key[pos] = ((u64)__float_as_uint(io) << 32) | (u64)(0xFFFFFFFFu - (u32)j);
        }
      }
    }
    __syncthreads();
  } else {
    // all positives + zero-fill with first (128-np) zero-iou cols ascending
    for (int t = tid; t < np; t += SEL_THR) {
      u64 k = s_pool[t];
      int pos = atomicAdd(&s_n2, 1);
      if (pos < SCAND) orow_key[pos] = k;
    }
    __syncthreads();
    if (tid < 64) {
      int need = SEL_TARGET - np, got = 0;
      int base_n = s_n2;
      for (int b2 = base; b2 < send && got < need; b2 += 64) {
        int j = b2 + tid;
        float io = (j < send) ? iou_f32(pbox[j], tb, area_t) : -1.0f;
        bool z = (j < send) && (io == 0.0f);
        u64 zm = __ballot(z);
        int rank = (int)__popcll(zm & ((1ull << tid) - 1ull));
        if (z && rank < need - got) {
          int pos = base_n + got + rank;
          if (pos < SCAND) orow_key[pos] = (u64)(0xFFFFFFFFu - (u32)j);
        }
        int zn = (int)__popcll(zm); if (zn > need - got) zn = need - got;
        got += zn;
      }
      if (tid == 0) s_n2 = base_n + got;
    }
    __syncthreads();
  }
  int n = min(s_n2, SCAND);
  for (int t2 = n + tid; t2 < SCAND; t2 += SEL_THR) orow_key[t2] = 0ull;
}

// owned-min DPP reduce step (identity: key=~0, col=INT_MAX)
#define DPP_STEP(CTRL) do { \
  u32 ohi = (u32)__builtin_amdgcn_update_dpp((int)0xFFFFFFFF, (int)khi, (CTRL), 0xF, 0xF, false); \
  u32 olo = (u32)__builtin_amdgcn_update_dpp((int)0xFFFFFFFF, (int)klo, (CTRL), 0xF, 0xF, false); \
  int ocl =      __builtin_amdgcn_update_dpp((int)0x7FFFFFFF, kcol,     (CTRL), 0xF, 0xF, false); \
  bool lt = (ohi < khi) || (ohi == khi && ((olo < klo) || (olo == klo && ocl < kcol))); \
  if (lt) { khi = ohi; klo = olo; kcol = ocl; } \
} while (0)

// head DPP max step (identity: 0)
#define DPPMAX(CTRL) do { \
  u32 oh2 = (u32)__builtin_amdgcn_update_dpp(0, (int)mhi, (CTRL), 0xF, 0xF, false); \
  u32 ol2 = (u32)__builtin_amdgcn_update_dpp(0, (int)mlo, (CTRL), 0xF, 0xF, false); \
  bool gt = (oh2 > mhi) || (oh2 == mhi && ol2 > mlo); \
  if (gt) { mhi = oh2; mlo = ol2; } \
} while (0)

// mask-filter pool keys, integer wave-max -> head_key (uniform)
#define STAGE_EVAL(KARR) do { \
  u64 lmax = 0; \
  _Pragma("unroll") \
  for (int s = 0; s < NSLOT; ++s) { \
    u64 k = (KARR)[s]; \
    if (k) { \
      u32 cw = 0xFFFFFFFFu - (u32)k; \
      if ((s_mask[cw >> 5] >> (cw & 31u)) & 1u) k = 0; \
      if (k > lmax) lmax = k; \
    } \
  } \
  u32 mhi = (u32)(lmax >> 32), mlo = (u32)lmax; \
  DPPMAX(0x111); DPPMAX(0x112); DPPMAX(0x114); DPPMAX(0x118); DPPMAX(0x142); DPPMAX(0x143); \
  u32 ghi = (u32)__builtin_amdgcn_readlane((int)mhi, 63); \
  u32 glo = (u32)__builtin_amdgcn_readlane((int)mlo, 63); \
  head_key = ((u64)ghi << 32) | (u64)glo; \
} while (0)

// cache iou of owned slots vs tbox[I0] (readlane broadcast)
#define RECOMP_IOU(I0) do { \
  int li = ((I0) - 1) & 63, hb = ((I0) - 1) >> 6; \
  float tx = __int_as_float(hb ? __builtin_amdgcn_readlane(__float_as_int(tbB.x), li) \
                               : __builtin_amdgcn_readlane(__float_as_int(tbA.x), li)); \
  float ty = __int_as_float(hb ? __builtin_amdgcn_readlane(__float_as_int(tbB.y), li) \
                               : __builtin_amdgcn_readlane(__float_as_int(tbA.y), li)); \
  float tz = __int_as_float(hb ? __builtin_amdgcn_readlane(__float_as_int(tbB.z), li) \
                               : __builtin_amdgcn_readlane(__float_as_int(tbA.z), li)); \
  float tw = __int_as_float(hb ? __builtin_amdgcn_readlane(__float_as_int(tbB.w), li) \
                               : __builtin_amdgcn_readlane(__float_as_int(tbA.w), li)); \
  float4 tbi = make_float4(tx, ty, tz, tw); \
  float ati = (tz - tx) * (tw - ty); \
  oi0 = iou_f32(ob0, tbi, ati); \
  oi1 = iou_f32(ob1, tbi, ati); \
} while (0)

// Kernel B: the serial buggy-JV matcher, 1 wave.
// Per-iteration: owned eval (stage-cached iou) + DPP min + uniform head compare.
// Head (best fresh) is an integer pool-max computed once per stage; fresh cost
// monotonic in io => head dominates all fresh (ties -> smaller col = head).
__global__ __launch_bounds__(64, 1) void match_kernel(const float4* __restrict__ pbox,
                                                      const float4* __restrict__ tboxg,
                                                      const u64* __restrict__ ckey,
                                                      int* __restrict__ pairs,
                                                      int M, int NROWS) {
  const int lane = threadIdx.x;
  __shared__ u32 s_mask[MASKW];
  for (int i = lane; i < MASKW; i += 64) s_mask[i] = 0;
  __syncthreads();

  float4 zf = make_float4(0.f, 0.f, 0.f, 0.f);
  float4 tbA = (lane < NROWS) ? tboxg[lane] : zf;
  float4 tbB = (lane + 64 < NROWS) ? tboxg[lane + 64] : zf;

  double u_a = 0.0, u_b = 0.0;          // u[lane+1], u[lane+65]
  int f_a = 0, f_b = 0;                 // in-chain flags
  int oc0 = -1, orow0 = 0, ovis0 = 0; double ov0 = 0.0; float4 ob0 = zf; float oi0 = 0.0f;
  int oc1 = -1, orow1 = 0, ovis1 = 0; double ov1 = 0.0; float4 ob1 = zf; float oi1 = 0.0f;
  int nown = 0;

  u64 pf[NSLOT];
  u64 head_key = 0;
  float4 hbox = zf;
  int row = 1, i0 = 1;
  double u_i0 = 0.0;

  {   // initial staging for row 1; prefetch row 2
#pragma unroll
    for (int s = 0; s < NSLOT; ++s) pf[s] = ckey[(s << 6) + lane];
    u64 ck[NSLOT];
#pragma unroll
    for (int s = 0; s < NSLOT; ++s) ck[s] = pf[s];
    int nr = (2 <= NROWS) ? 2 : 1;
    const u64* kp = ckey + (size_t)(nr - 1) * CAND;
#pragma unroll
    for (int s = 0; s < NSLOT; ++s) pf[s] = kp[(s << 6) + lane];
    STAGE_EVAL(ck);
    hbox = pbox[0xFFFFFFFFu - (u32)head_key];
    f_a = (lane == 0); f_b = 0;
    u_i0 = 0.0;
  }

  for (int guard = 0; guard < 5000; ++guard) {
    if (head_key == 0) break;           // unreachable (pool>=128 legit, owned<=127)

    // ---- owned eval: registers only (iou cached at stage) ----
    u32 bhi = 0xFFFFFFFFu, blo = 0xFFFFFFFFu; int bcol = 0x7fffffff; int bsl = 15;
    if (oc0 >= 0 && ovis0 != row) {
      double cur = ((-(double)oi0) - u_i0) - ov0;    // exact reference f64 op order
      u64 mk = map_cost(cur);
      bhi = (u32)(mk >> 32); blo = (u32)mk; bcol = oc0; bsl = 6;
    }
    if (oc1 >= 0 && ovis1 != row) {
      double cur = ((-(double)oi1) - u_i0) - ov1;
      u64 mk = map_cost(cur);
      u32 hi = (u32)(mk >> 32), lo = (u32)mk;
      bool t = (hi < bhi) || (hi == bhi && ((lo < blo) || (lo == blo && oc1 < bcol)));
      if (t) { bhi = hi; blo = lo; bcol = oc1; bsl = 7; }
    }
    u32 khi = bhi, klo = blo; int kcol = bcol;
    DPP_STEP(0x111); DPP_STEP(0x112); DPP_STEP(0x114); DPP_STEP(0x118);
    DPP_STEP(0x142); DPP_STEP(0x143);
    u32 rhi = (u32)__builtin_amdgcn_readlane((int)khi, 63);
    u32 rlo = (u32)__builtin_amdgcn_readlane((int)klo, 63);
    int rcol = __builtin_amdgcn_readlane(kcol, 63);

    // ---- head cost (fresh best; v==0 exact) ----
    float hio = __uint_as_float((u32)(head_key >> 32));
    int hcol = (int)(0xFFFFFFFFu - (u32)head_key);
    double curh = (-(double)hio) - u_i0;             // == ((-io)-u)-0.0 bitwise
    u64 mh = map_cost(curh);
    u32 hhi = (u32)(mh >> 32), hlo = (u32)mh;
    bool head_wins = (hhi < rhi) || (hhi == rhi && ((hlo < rlo) || (hlo == rlo && hcol < rcol)));
    const double delta = unmap_cost(head_wins ? mh : (((u64)rhi << 32) | (u64)rlo));

    // ---- updates: u[p[used]] += delta ; v[used] -= delta (pre-append used set) ----
    if (f_a) u_a += delta;
    if (f_b) u_b += delta;
    u_i0 += delta;
    if (oc0 >= 0 && ovis0 == row) ov0 -= delta;
    if (oc1 >= 0 && ovis1 == row) ov1 -= delta;

    if (head_wins) {
      // ---- augment: way==0 collapses to single assignment p[hcol]=row ----
      if (lane == 0) {
        pairs[row - 1] = hcol;
        atomicOr(&s_mask[(u32)hcol >> 5], 1u << ((u32)hcol & 31u));
      }
      int ne = nown, nl = ne & 63, nh = ne >> 6;
      if (lane == nl) {
        if (nh == 0) { oc0 = hcol; orow0 = row; ovis0 = 0; ov0 = 0.0; ob0 = hbox; }
        else         { oc1 = hcol; orow1 = row; ovis1 = 0; ov1 = 0.0; ob1 = hbox; }
      }
      nown = ne + 1;
      if (row == NROWS) break;
      ++row; i0 = row;
      asm volatile("s_waitcnt lgkmcnt(0)" ::: "memory");  // order atomicOr vs mask reads
      {   // stage row: consume prefetched pool, issue next prefetch
        u64 ck[NSLOT];
#pragma unroll
        for (int s = 0; s < NSLOT; ++s) ck[s] = pf[s];
        int nr = (row < NROWS) ? row + 1 : row;
        const u64* kp = ckey + (size_t)(nr - 1) * CAND;
#pragma unroll
        for (int s = 0; s < NSLOT; ++s) pf[s] = kp[(s << 6) + lane];
        STAGE_EVAL(ck);
        hbox = pbox[0xFFFFFFFFu - (u32)head_key];
        RECOMP_IOU(row);
        f_a = (lane == ((row - 1) & 63)) && (((row - 1) >> 6) == 0);
        f_b = (lane == ((row - 1) & 63)) && (((row - 1) >> 6) == 1);
        u_i0 = 0.0;
      }
    } else {
      // ---- chain to owner row ----
      bool eq = (bhi == rhi) && (blo == rlo) && (bcol == rcol);
      u64 wm = __ballot(eq);
      int L = (int)__ffsll((long long)wm) - 1;
      L = __builtin_amdgcn_readfirstlane(L);
      int s_w = __builtin_amdgcn_readlane(bsl, L);
      int o = __builtin_amdgcn_readlane((s_w == 6) ? orow0 : orow1, L);
      o = __builtin_amdgcn_readfirstlane(o);
      if (lane == L) { if (s_w == 6) ovis0 = row; else ovis1 = row; }
      int ol = (o - 1) & 63, oh = (o - 1) >> 6;
      if (lane == ol) { if (oh == 0) f_a = 1; else f_b = 1; }
      double uo = oh ? u_b : u_a;
      int uhi2 = __builtin_amdgcn_readlane(__double2hiint(uo), ol);
      int ulo2 = __builtin_amdgcn_readlane(__double2loint(uo), ol);
      u_i0 = __hiloint2double(uhi2, ulo2);
      i0 = o;
      {   // stage chain row (cold, rare)
        u64 ck[NSLOT];
        const u64* kp = ckey + (size_t)(o - 1) * CAND;
#pragma unroll
        for (int s = 0; s < NSLOT; ++s) ck[s] = kp[(s << 6) + lane];
        STAGE_EVAL(ck);
        hbox = pbox[0xFFFFFFFFu - (u32)head_key];
        RECOMP_IOU(o);
      }
    }
  }
}

__global__ __launch_bounds__(256) void loss_kernel(const float4* __restrict__ pbox,
                                                   const float* __restrict__ confs,
                                                   const float4* __restrict__ tbox,
                                                   const int* __restrict__ tlab,
                                                   const int* __restrict__ pairs,
                                                   float* __restrict__ out,
                                                   int NROWS, int C) {
  const int tid = threadIdx.x;
  __shared__ float s_reg[256];
  __shared__ float s_cls[256];
  __shared__ int   s_acc[256];
  float reg = 0.0f, cls = 0.0f; int acc = 0;
  if (tid < NROWS) {
    int pred = pairs[tid];
    float4 pb = pbox[pred];
    float4 tb = tbox[tid];
    float d0 = pb.x - tb.x, d1 = pb.y - tb.y, d2 = pb.z - tb.z, d3 = pb.w - tb.w;
    float a0 = fabsf(d0), a1 = fabsf(d1), a2 = fabsf(d2), a3 = fabsf(d3);
    float s = 0.0f;
    s += (a0 < 1.0f) ? 0.5f * d0 * d0 : a0 - 0.5f;
    s += (a1 < 1.0f) ? 0.5f * d1 * d1 : a1 - 0.5f;
    s += (a2 < 1.0f) ? 0.5f * d2 * d2 : a2 - 0.5f;
    s += (a3 < 1.0f) ? 0.5f * d3 * d3 : a3 - 0.5f;
    reg = s * 0.25f;

    const float* lg = confs + (long long)pred * C;
    float mx = lg[0]; int am = 0;
    for (int k = 1; k < C; ++k) { float x = lg[k]; if (x > mx) { mx = x; am = k; } }
    double se = 0.0;
    for (int k = 0; k < C; ++k) se += exp((double)(lg[k] - mx));
    int lab = tlab[tid];
    double logp = (double)(lg[lab] - mx) - log(se);
    cls = (float)(-logp);
    acc = (am == lab) ? 1 : 0;
  }
  s_reg[tid] = reg; s_cls[tid] = cls; s_acc[tid] = acc;
  __syncthreads();
  for (int s2 = 128; s2 > 0; s2 >>= 1) {
    if (tid < s2) {
      s_reg[tid] += s_reg[tid + s2];
      s_cls[tid] += s_cls[tid + s2];
      s_acc[tid] += s_acc[tid + s2];
    }
    __syncthreads();
  }
  if (tid == 0) {
    out[0] = s_reg[0] + s_cls[0];
    out[1] = (float)s_acc[0];
  }
}

extern "C" void kernel_launch(void* const* d_in, const int* in_sizes, int n_in,
                              void* d_out, int out_size, void* d_ws, size_t ws_size,
                              hipStream_t stream) {
  const float4* pbox  = (const float4*)d_in[0];
  const float*  confs = (const float*)d_in[1];
  const float4* tbox  = (const float4*)d_in[2];
  const int*    tlab  = (const int*)d_in[3];

  int N = in_sizes[0] / 4;          // 100000 predictions (columns)
  int C = in_sizes[1] / N;          // 81 classes
  int NROWS = in_sizes[2] / 4;      // 128 targets (rows), <=128 supported
  int M = N;

  char* w = (char*)d_ws;
  auto alloc = [&](size_t sz) { char* r = w; w += (sz + 255) & ~(size_t)255; return r; };
  u64* ckey  = (u64*)alloc((size_t)NROWS * CAND * sizeof(u64));
  int* pairs = (int*)alloc((size_t)(NROWS + 8) * sizeof(int));

  select_kernel<<<dim3(SLICES, NROWS), SEL_THR, 0, stream>>>(pbox, tbox, ckey, M, NROWS);
  match_kernel<<<1, 64, 0, stream>>>(pbox, tbox, ckey, pairs, M, NROWS);
  loss_kernel<<<1, 256, 0, stream>>>(pbox, confs, tbox, tlab, pairs,
                                     (float*)d_out, NROWS, C);
}

// Round 9
// 251.226 us; speedup vs baseline: 2.4801x; 1.2331x over previous
//
#include <hip/hip_runtime.h>
#include <cstdint>
#include <cstddef>

typedef unsigned long long u64;
typedef unsigned int u32;

#define SLICES 2
#define SCAND 192           // per-slice pool capacity
#define CAND 384            // SLICES * SCAND
#define NSLOT 6             // CAND / 64
#define NBINS 4096
#define SEL_THR 1024
#define SEL_TARGET 128
#define POOLCAP 4096
#define MASKW 3200          // 102400 columns max as bits
#define TOP8 8

// IoU exactly as reference _box_iou, all f32 IEEE ops (bit-exact, absmax=0 rounds 1-8).
__device__ __forceinline__ float iou_f32(float4 p, float4 t, float area_t) {
  float area1 = (p.z - p.x) * (p.w - p.y);
  float ltx = fmaxf(p.x, t.x);
  float lty = fmaxf(p.y, t.y);
  float rbx = fminf(p.z, t.z);
  float rby = fminf(p.w, t.w);
  float wx = fmaxf(rbx - ltx, 0.0f);
  float wy = fmaxf(rby - lty, 0.0f);
  float inter = wx * wy;
  return inter / (area1 + area_t - inter);
}

__device__ __forceinline__ u64 map_cost(double cur) {
  u64 b = (u64)__double_as_longlong(cur);
  if (b == 0x8000000000000000ull) b = 0;                 // canonicalize -0 -> +0
  return (b >> 63) ? ~b : (b | 0x8000000000000000ull);   // order-exact total map
}
__device__ __forceinline__ double unmap_cost(u64 m) {
  u64 b = (m >> 63) ? (m ^ 0x8000000000000000ull) : ~m;
  return __longlong_as_double((long long)b);
}

// Key encoding: (io_bits << 32) | (0xFFFFFFFF - col). Raw u64 max = (io desc, col asc).
// Padding = 0 — never beats a legit entry.

// Kernel A: unchanged from round 8 (proven absmax=0). Per (slice,row): positives
// pool + histogram; threshold B = highest bin with suffix>=128; filtered pool
// (superset of per-slice top-128 by iou) written as keys; tail padded 0.
__global__ __launch_bounds__(SEL_THR) void select_kernel(const float4* __restrict__ pbox,
                                                         const float4* __restrict__ tbox,
                                                         u64* __restrict__ ckey,
                                                         int M, int NROWS) {
  __shared__ u32 s_hist[NBINS];
  __shared__ int s_csum[SEL_THR];
  __shared__ u64 s_pool[POOLCAP];
  __shared__ int s_n, s_n2, s_B;
  const int tid = threadIdx.x;
  const int lane = tid & 63;
  const int slice = blockIdx.x, row = blockIdx.y;
  const int sw = (M + SLICES - 1) / SLICES;
  const int base = slice * sw;
  const int send = min(base + sw, M);
  const float4 tb = tbox[row];
  const float area_t = (tb.z - tb.x) * (tb.w - tb.y);
  u64* orow_key = ckey + (size_t)row * CAND + slice * SCAND;

  for (int b = tid; b < NBINS; b += SEL_THR) s_hist[b] = 0;
  if (tid == 0) { s_n = 0; s_n2 = 0; s_B = 0; }
  __syncthreads();

  const u64 lowmask = (1ull << lane) - 1ull;
  const int iters = (sw + SEL_THR - 1) / SEL_THR;
  for (int it = 0; it < iters; ++it) {
    int j = base + it * SEL_THR + tid;
    bool inr = (j < send);
    float io = -1.0f;
    if (inr) io = iou_f32(pbox[j], tb, area_t);
    bool pos = inr && (io > 0.0f);
    u64 pm = __ballot(pos);
    int wn = (int)__popcll(pm);
    if (wn) {
      int wb = 0;
      if (lane == 0) wb = atomicAdd(&s_n, wn);
      wb = __shfl(wb, 0);
      if (pos) {
        int idx = wb + (int)__popcll(pm & lowmask);
        if (idx < POOLCAP) s_pool[idx] = ((u64)__float_as_uint(io) << 32) | (u64)(0xFFFFFFFFu - (u32)j);
        atomicAdd(&s_hist[__float_as_uint(io) >> 18], 1u);
      }
    }
  }
  __syncthreads();
  const int np = s_n;

  {
    int b0 = tid * 4;
    s_csum[tid] = (int)(s_hist[b0] + s_hist[b0 + 1] + s_hist[b0 + 2] + s_hist[b0 + 3]);
  }
  __syncthreads();

  if (tid < 64) {
    if (np >= SEL_TARGET) {
      int R = 0; bool found = false;
      for (int ch = SEL_THR / 64 - 1; ch >= 0 && !found; --ch) {
        int cum = s_csum[ch * 64 + tid];
        for (int off = 1; off < 64; off <<= 1) {
          int o = __shfl_down(cum, off);
          if (tid + off < 64) cum += o;
        }
        int chunksum = __shfl(cum, 0);
        if (R + chunksum >= SEL_TARGET) {
          u64 m = __ballot(R + cum >= SEL_TARGET);
          int l = 63 - __clzll(m);
          int R2 = R + ((l < 63) ? __shfl(cum, l + 1) : 0);
          if (tid == 0) {
            int bb = (ch * 64 + l) * 4;
            int B2 = bb;
            for (int b = bb + 3; b >= bb; --b) {
              R2 += (int)s_hist[b];
              if (R2 >= SEL_TARGET) { B2 = b; break; }
            }
            s_B = B2;
          }
          found = true;
        } else R += chunksum;
      }
    }
  }
  __syncthreads();
  const int B = s_B;

  if (np >= SEL_TARGET) {
    if (np <= POOLCAP) {
      for (int t = tid; t < np; t += SEL_THR) {
        u64 k = s_pool[t];
        if ((u32)(k >> 50) >= (u32)B) {
          int pos = atomicAdd(&s_n2, 1);
          if (pos < SCAND) orow_key[pos] = k;
        }
      }
    } else {
      for (int j = base + tid; j < send; j += SEL_THR) {
        float io = iou_f32(pbox[j], tb, area_t);
        if (io > 0.0f && (int)(__float_as_uint(io) >> 18) >= B) {
          int pos = atomicAdd(&s_n2, 1);
          if (pos < SCAND) orow_key[pos] = ((u64)__float_as_uint(io) << 32) | (u64)(0xFFFFFFFFu - (u32)j);
        }
      }
    }
    __syncthreads();
  } else {
    for (int t = tid; t < np; t += SEL_THR) {
      u64 k = s_pool[t];
      int pos = atomicAdd(&s_n2, 1);
      if (pos < SCAND) orow_key[pos] = k;
    }
    __syncthreads();
    if (tid < 64) {
      int need = SEL_TARGET - np, got = 0;
      int base_n = s_n2;
      for (int b2 = base; b2 < send && got < need; b2 += 64) {
        int j = b2 + tid;
        float io = (j < send) ? iou_f32(pbox[j], tb, area_t) : -1.0f;
        bool z = (j < send) && (io == 0.0f);
        u64 zm = __ballot(z);
        int rank = (int)__popcll(zm & ((1ull << tid) - 1ull));
        if (z && rank < need - got) {
          int pos = base_n + got + rank;
          if (pos < SCAND) orow_key[pos] = (u64)(0xFFFFFFFFu - (u32)j);
        }
        int zn = (int)__popcll(zm); if (zn > need - got) zn = need - got;
        got += zn;
      }
      if (tid == 0) s_n2 = base_n + got;
    }
    __syncthreads();
  }
  int n = min(s_n2, SCAND);
  for (int t2 = n + tid; t2 < SCAND; t2 += SEL_THR) orow_key[t2] = 0ull;
}

// owned-min DPP reduce step (identity: key=~0, col=INT_MAX)
#define DPP_STEP(CTRL) do { \
  u32 ohi = (u32)__builtin_amdgcn_update_dpp((int)0xFFFFFFFF, (int)khi, (CTRL), 0xF, 0xF, false); \
  u32 olo = (u32)__builtin_amdgcn_update_dpp((int)0xFFFFFFFF, (int)klo, (CTRL), 0xF, 0xF, false); \
  int ocl =      __builtin_amdgcn_update_dpp((int)0x7FFFFFFF, kcol,     (CTRL), 0xF, 0xF, false); \
  bool lt = (ohi < khi) || (ohi == khi && ((olo < klo) || (olo == klo && ocl < kcol))); \
  if (lt) { khi = ohi; klo = olo; kcol = ocl; } \
} while (0)

// max DPP step (identity: 0)
#define DPPMAX(CTRL) do { \
  u32 oh2 = (u32)__builtin_amdgcn_update_dpp(0, (int)mhi, (CTRL), 0xF, 0xF, false); \
  u32 ol2 = (u32)__builtin_amdgcn_update_dpp(0, (int)mlo, (CTRL), 0xF, 0xF, false); \
  bool gt = (oh2 > mhi) || (oh2 == mhi && ol2 > mlo); \
  if (gt) { mhi = oh2; mlo = ol2; } \
} while (0)

// Kernel A2: exact top-8 of each row's pool by u64 key (DPP-max + tombstone).
__global__ __launch_bounds__(64) void top8_kernel(const u64* __restrict__ ckey,
                                                  u64* __restrict__ top8g, int NROWS) {
  const int lane = threadIdx.x;
  const int row = blockIdx.x;
  const u64* kp = ckey + (size_t)row * CAND;
  u64 k[NSLOT];
#pragma unroll
  for (int s = 0; s < NSLOT; ++s) k[s] = kp[(s << 6) + lane];
  u64 out = 0;
  for (int r = 0; r < TOP8; ++r) {
    u64 lmax = 0;
#pragma unroll
    for (int s = 0; s < NSLOT; ++s) if (k[s] > lmax) lmax = k[s];
    u32 mhi = (u32)(lmax >> 32), mlo = (u32)lmax;
    DPPMAX(0x111); DPPMAX(0x112); DPPMAX(0x114); DPPMAX(0x118); DPPMAX(0x142); DPPMAX(0x143);
    u32 ghi = (u32)__builtin_amdgcn_readlane((int)mhi, 63);
    u32 glo = (u32)__builtin_amdgcn_readlane((int)mlo, 63);
    u64 g = ((u64)ghi << 32) | (u64)glo;
    if (lane == r) out = g;
#pragma unroll
    for (int s = 0; s < NSLOT; ++s) if (k[s] == g) k[s] = 0;   // keys unique
  }
  if (lane < TOP8) top8g[(size_t)row * TOP8 + lane] = out;
}

// full-pool head (fallback): mask-filter + 64-lane DPP max
#define STAGE_EVAL(KARR) do { \
  u64 lmax = 0; \
  _Pragma("unroll") \
  for (int s = 0; s < NSLOT; ++s) { \
    u64 k = (KARR)[s]; \
    if (k) { \
      u32 cw = 0xFFFFFFFFu - (u32)k; \
      if ((s_mask[cw >> 5] >> (cw & 31u)) & 1u) k = 0; \
      if (k > lmax) lmax = k; \
    } \
  } \
  u32 mhi = (u32)(lmax >> 32), mlo = (u32)lmax; \
  DPPMAX(0x111); DPPMAX(0x112); DPPMAX(0x114); DPPMAX(0x118); DPPMAX(0x142); DPPMAX(0x143); \
  u32 ghi = (u32)__builtin_amdgcn_readlane((int)mhi, 63); \
  u32 glo = (u32)__builtin_amdgcn_readlane((int)mlo, 63); \
  head_key = ((u64)ghi << 32) | (u64)glo; \
} while (0)

// LDS stage: head = max over top8[rr] minus owned; 0 -> cold full-pool fallback.
// Exact: if any of the exact top-8 is unowned, the global unowned max is among them.
#define STAGE_LDS(RR) do { \
  u64 k = 0; \
  if (lane < TOP8) { \
    k = s_top8[(RR) - 1][lane]; \
    u32 cw = 0xFFFFFFFFu - (u32)k; \
    if ((s_mask[cw >> 5] >> (cw & 31u)) & 1u) k = 0; \
  } \
  u32 mhi = (u32)(k >> 32), mlo = (u32)k; \
  DPPMAX(0x111); DPPMAX(0x112); DPPMAX(0x114); \
  u32 ghi = (u32)__builtin_amdgcn_readlane((int)mhi, 7); \
  u32 glo = (u32)__builtin_amdgcn_readlane((int)mlo, 7); \
  head_key = ((u64)ghi << 32) | (u64)glo; \
  if (head_key == 0) { \
    u64 ck[NSLOT]; \
    const u64* kp = ckey + (size_t)((RR) - 1) * CAND; \
    _Pragma("unroll") \
    for (int s = 0; s < NSLOT; ++s) ck[s] = kp[(s << 6) + lane]; \
    STAGE_EVAL(ck); \
  } \
} while (0)

// cache iou of owned slots vs tbox[I0] (LDS broadcast read)
#define RECOMP_IOU(I0) do { \
  float4 tbi = s_tb[(I0) - 1]; \
  float ati = s_ta[(I0) - 1]; \
  oi0 = iou_f32(ob0, tbi, ati); \
  oi1 = iou_f32(ob1, tbi, ati); \
} while (0)

// Kernel B: the serial buggy-JV matcher, 1 wave, LDS-resident staging.
// Invariants: visited => owned; v!=0 => owned; ownership frozen during a search.
__global__ __launch_bounds__(64, 1) void match_kernel(const float4* __restrict__ pbox,
                                                      const float4* __restrict__ tboxg,
                                                      const u64* __restrict__ ckey,
                                                      const u64* __restrict__ top8g,
                                                      int* __restrict__ pairs,
                                                      int M, int NROWS) {
  const int lane = threadIdx.x;
  __shared__ u32 s_mask[MASKW];
  __shared__ u64 s_top8[128][TOP8];
  __shared__ float4 s_tb[128];
  __shared__ float  s_ta[128];

  for (int i = lane; i < MASKW; i += 64) s_mask[i] = 0;
  for (int i = lane; i < NROWS; i += 64) {
    float4 t = tboxg[i];
    s_tb[i] = t;
    s_ta[i] = (t.z - t.x) * (t.w - t.y);
  }
  for (int i = lane; i < NROWS * TOP8; i += 64) s_top8[i >> 3][i & 7] = top8g[i];
  __syncthreads();

  float4 zf = make_float4(0.f, 0.f, 0.f, 0.f);
  double u_a = 0.0, u_b = 0.0;          // u[lane+1], u[lane+65]
  int f_a = 0, f_b = 0;                 // in-chain flags
  int oc0 = -1, orow0 = 0, ovis0 = 0; double ov0 = 0.0; float4 ob0 = zf; float oi0 = 0.0f;
  int oc1 = -1, orow1 = 0, ovis1 = 0; double ov1 = 0.0; float4 ob1 = zf; float oi1 = 0.0f;
  int nown = 0;

  u64 head_key = 0;
  float4 hbox = zf;
  int row = 1, i0 = 1;
  double u_i0 = 0.0;

  STAGE_LDS(1);
  hbox = pbox[0xFFFFFFFFu - (u32)head_key];
  f_a = (lane == 0); f_b = 0;
  u_i0 = 0.0;

  for (int guard = 0; guard < 5000; ++guard) {
    if (head_key == 0) break;           // unreachable safety

    // ---- owned eval: registers only (iou cached at stage) ----
    u32 bhi = 0xFFFFFFFFu, blo = 0xFFFFFFFFu; int bcol = 0x7fffffff; int bsl = 15;
    if (oc0 >= 0 && ovis0 != row) {
      double cur = ((-(double)oi0) - u_i0) - ov0;    // exact reference f64 op order
      u64 mk = map_cost(cur);
      bhi = (u32)(mk >> 32); blo = (u32)mk; bcol = oc0; bsl = 6;
    }
    if (oc1 >= 0 && ovis1 != row) {
      double cur = ((-(double)oi1) - u_i0) - ov1;
      u64 mk = map_cost(cur);
      u32 hi = (u32)(mk >> 32), lo = (u32)mk;
      bool t = (hi < bhi) || (hi == bhi && ((lo < blo) || (lo == blo && oc1 < bcol)));
      if (t) { bhi = hi; blo = lo; bcol = oc1; bsl = 7; }
    }
    u32 khi = bhi, klo = blo; int kcol = bcol;
    DPP_STEP(0x111); DPP_STEP(0x112); DPP_STEP(0x114); DPP_STEP(0x118);
    DPP_STEP(0x142); DPP_STEP(0x143);
    u32 rhi = (u32)__builtin_amdgcn_readlane((int)khi, 63);
    u32 rlo = (u32)__builtin_amdgcn_readlane((int)klo, 63);
    int rcol = __builtin_amdgcn_readlane(kcol, 63);

    // ---- head cost (fresh best; v==0 exact) ----
    float hio = __uint_as_float((u32)(head_key >> 32));
    int hcol = (int)(0xFFFFFFFFu - (u32)head_key);
    double curh = (-(double)hio) - u_i0;             // == ((-io)-u)-0.0 bitwise
    u64 mh = map_cost(curh);
    u32 hhi = (u32)(mh >> 32), hlo = (u32)mh;
    bool head_wins = (hhi < rhi) || (hhi == rhi && ((hlo < rlo) || (hlo == rlo && hcol < rcol)));
    const double delta = unmap_cost(head_wins ? mh : (((u64)rhi << 32) | (u64)rlo));

    // ---- updates: u[p[used]] += delta ; v[used] -= delta (pre-append used set) ----
    if (f_a) u_a += delta;
    if (f_b) u_b += delta;
    u_i0 += delta;
    if (oc0 >= 0 && ovis0 == row) ov0 -= delta;
    if (oc1 >= 0 && ovis1 == row) ov1 -= delta;

    if (head_wins) {
      // ---- augment: way==0 collapses to single assignment p[hcol]=row ----
      if (lane == 0) {
        pairs[row - 1] = hcol;
        atomicOr(&s_mask[(u32)hcol >> 5], 1u << ((u32)hcol & 31u));
      }
      int ne = nown, nl = ne & 63, nh = ne >> 6;
      if (lane == nl) {
        if (nh == 0) { oc0 = hcol; orow0 = row; ovis0 = 0; ov0 = 0.0; ob0 = hbox; }
        else         { oc1 = hcol; orow1 = row; ovis1 = 0; ov1 = 0.0; ob1 = hbox; }
      }
      nown = ne + 1;
      if (row == NROWS) break;
      ++row; i0 = row;
      asm volatile("s_waitcnt lgkmcnt(0)" ::: "memory");  // mask write visible to stage reads
      STAGE_LDS(row);
      hbox = pbox[0xFFFFFFFFu - (u32)head_key];
      RECOMP_IOU(row);
      f_a = (lane == ((row - 1) & 63)) && (((row - 1) >> 6) == 0);
      f_b = (lane == ((row - 1) & 63)) && (((row - 1) >> 6) == 1);
      u_i0 = 0.0;
    } else {
      // ---- chain to owner row ----
      bool eq = (bhi == rhi) && (blo == rlo) && (bcol == rcol);
      u64 wm = __ballot(eq);
      int L = (int)__ffsll((long long)wm) - 1;
      L = __builtin_amdgcn_readfirstlane(L);
      int s_w = __builtin_amdgcn_readlane(bsl, L);
      int o = __builtin_amdgcn_readlane((s_w == 6) ? orow0 : orow1, L);
      o = __builtin_amdgcn_readfirstlane(o);
      if (lane == L) { if (s_w == 6) ovis0 = row; else ovis1 = row; }
      int ol = (o - 1) & 63, oh = (o - 1) >> 6;
      if (lane == ol) { if (oh == 0) f_a = 1; else f_b = 1; }
      double uo = oh ? u_b : u_a;
      int uhi2 = __builtin_amdgcn_readlane(__double2hiint(uo), ol);
      int ulo2 = __builtin_amdgcn_readlane(__double2loint(uo), ol);
      u_i0 = __hiloint2double(uhi2, ulo2);
      i0 = o;
      STAGE_LDS(o);
      hbox = pbox[0xFFFFFFFFu - (u32)head_key];
      RECOMP_IOU(o);
    }
  }
}

__global__ __launch_bounds__(256) void loss_kernel(const float4* __restrict__ pbox,
                                                   const float* __restrict__ confs,
                                                   const float4* __restrict__ tbox,
                                                   const int* __restrict__ tlab,
                                                   const int* __restrict__ pairs,
                                                   float* __restrict__ out,
                                                   int NROWS, int C) {
  const int tid = threadIdx.x;
  __shared__ float s_reg[256];
  __shared__ float s_cls[256];
  __shared__ int   s_acc[256];
  float reg = 0.0f, cls = 0.0f; int acc = 0;
  if (tid < NROWS) {
    int pred = pairs[tid];
    float4 pb = pbox[pred];
    float4 tb = tbox[tid];
    float d0 = pb.x - tb.x, d1 = pb.y - tb.y, d2 = pb.z - tb.z, d3 = pb.w - tb.w;
    float a0 = fabsf(d0), a1 = fabsf(d1), a2 = fabsf(d2), a3 = fabsf(d3);
    float s = 0.0f;
    s += (a0 < 1.0f) ? 0.5f * d0 * d0 : a0 - 0.5f;
    s += (a1 < 1.0f) ? 0.5f * d1 * d1 : a1 - 0.5f;
    s += (a2 < 1.0f) ? 0.5f * d2 * d2 : a2 - 0.5f;
    s += (a3 < 1.0f) ? 0.5f * d3 * d3 : a3 - 0.5f;
    reg = s * 0.25f;

    const float* lg = confs + (long long)pred * C;
    float mx = lg[0]; int am = 0;
    for (int k = 1; k < C; ++k) { float x = lg[k]; if (x > mx) { mx = x; am = k; } }
    double se = 0.0;
    for (int k = 0; k < C; ++k) se += exp((double)(lg[k] - mx));
    int lab = tlab[tid];
    double logp = (double)(lg[lab] - mx) - log(se);
    cls = (float)(-logp);
    acc = (am == lab) ? 1 : 0;
  }
  s_reg[tid] = reg; s_cls[tid] = cls; s_acc[tid] = acc;
  __syncthreads();
  for (int s2 = 128; s2 > 0; s2 >>= 1) {
    if (tid < s2) {
      s_reg[tid] += s_reg[tid + s2];
      s_cls[tid] += s_cls[tid + s2];
      s_acc[tid] += s_acc[tid + s2];
    }
    __syncthreads();
  }
  if (tid == 0) {
    out[0] = s_reg[0] + s_cls[0];
    out[1] = (float)s_acc[0];
  }
}

extern "C" void kernel_launch(void* const* d_in, const int* in_sizes, int n_in,
                              void* d_out, int out_size, void* d_ws, size_t ws_size,
                              hipStream_t stream) {
  const float4* pbox  = (const float4*)d_in[0];
  const float*  confs = (const float*)d_in[1];
  const float4* tbox  = (const float4*)d_in[2];
  const int*    tlab  = (const int*)d_in[3];

  int N = in_sizes[0] / 4;          // 100000 predictions (columns)
  int C = in_sizes[1] / N;          // 81 classes
  int NROWS = in_sizes[2] / 4;      // 128 targets (rows), <=128 supported
  int M = N;

  char* w = (char*)d_ws;
  auto alloc = [&](size_t sz) { char* r = w; w += (sz + 255) & ~(size_t)255; return r; };
  u64* ckey  = (u64*)alloc((size_t)NROWS * CAND * sizeof(u64));
  u64* top8g = (u64*)alloc((size_t)NROWS * TOP8 * sizeof(u64));
  int* pairs = (int*)alloc((size_t)(NROWS + 8) * sizeof(int));

  select_kernel<<<dim3(SLICES, NROWS), SEL_THR, 0, stream>>>(pbox, tbox, ckey, M, NROWS);
  top8_kernel<<<NROWS, 64, 0, stream>>>(ckey, top8g, NROWS);
  match_kernel<<<1, 64, 0, stream>>>(pbox, tbox, ckey, top8g, pairs, M, NROWS);
  loss_kernel<<<1, 256, 0, stream>>>(pbox, confs, tbox, tlab, pairs,
                                     (float*)d_out, NROWS, C);
}